// Round 15
// baseline (410.936 us; speedup 1.0000x reference)
//
#include <hip/hip_runtime.h>
#include <hip/hip_bf16.h>
#include <math.h>

#define B_   8
#define N_   1024
#define D_   512
#define H_   8
#define HD_  64
#define D3_  1536
#define M_   (B_ * N_)   // 8192 tokens per branch; 16384 combined

// bf16 weight-pool offsets (elements)
#define WOFF_SQ    0
#define WOFF_PQ    786432
#define WOFF_SPROJ 1572864
#define WOFF_PPROJ 1835008
#define WOFF_VF1   2097152
#define WOFF_VF2   2621440
#define WOFF_FR1   3145728
#define WOFF_FR2   3670016

typedef float f32x4 __attribute__((ext_vector_type(4)));
typedef __bf16 bf16x8 __attribute__((ext_vector_type(8)));

union FragU {
    uint4 u4;
    unsigned int u[4];
    ushort s[8];
    bf16x8 v;
};

static __device__ __forceinline__ ushort f2bf(float x) {
    union { __bf16 h; ushort u; } c;
    c.h = (__bf16)x;
    return c.u;
}

static __device__ __forceinline__ float bf2f(ushort u) {
    union { unsigned u; float f; } c;
    c.u = ((unsigned)u) << 16;
    return c.f;
}

static __device__ __forceinline__ unsigned int pack2(float a, float b) {
    return (unsigned int)f2bf(a) | ((unsigned int)f2bf(b) << 16);
}

static __device__ __forceinline__ float gelu_f(float x) {
    return 0.5f * x * (1.0f + erff(x * 0.7071067811865475f));
}

#if __has_builtin(__builtin_amdgcn_exp2f)
static __device__ __forceinline__ float exp2_fast(float x) { return __builtin_amdgcn_exp2f(x); }
#else
static __device__ __forceinline__ float exp2_fast(float x) { return exp2f(x); }
#endif

// async global->LDS, 16B per lane; lds base must be wave-uniform
static __device__ __forceinline__ void gload16(const ushort* g, ushort* lds) {
    __builtin_amdgcn_global_load_lds(
        (const __attribute__((address_space(1))) void*)g,
        (__attribute__((address_space(3))) void*)lds, 16, 0, 0);
}

// block-wide sum, blockDim.x == 256 (4 waves)
static __device__ __forceinline__ float blk_sum(float v, float* red) {
    #pragma unroll
    for (int off = 32; off; off >>= 1) v += __shfl_xor(v, off);
    const int w = threadIdx.x >> 6;
    __syncthreads();
    if ((threadIdx.x & 63) == 0) red[w] = v;
    __syncthreads();
    return red[0] + red[1] + red[2] + red[3];
}

// ---------------------------------------------------------------------------
// bf16 MFMA GEMM (BK=32, fragment-major LDS, global_load_lds, 2-phase
// prefetch). Templated BMxBN tile, 4 waves.
// GROUP: rows >= Msplit use Wt2/bias2 (two-branch batched GEMM).
// OUT: 0 = f32; 1 = bf16.  ACT: 1 = exact GELU.
// FINAL: C = bf2f(fusedb) + alpha*(acc+bias) + beta*bf2f(resb)   (f32 out)
// XCD-chunked swizzle (grid % 8 == 0), m-major block order.
// ---------------------------------------------------------------------------
template <int BM, int BN, int ACT, int OUT, bool FINAL, bool GROUP>
__global__ __launch_bounds__(256) void pgemm_k(
    const ushort* __restrict__ A, const ushort* __restrict__ Wt,
    const ushort* __restrict__ Wt2, const float* __restrict__ bias,
    const float* __restrict__ bias2, int Msplit,
    void* __restrict__ Cv, int nbx, int Nn, int K,
    const ushort* __restrict__ fusedb, const ushort* __restrict__ resb,
    const float* __restrict__ alphap, const float* __restrict__ betap)
{
    constexpr int MI = BM / 32;     // A frags per wave
    constexpr int NJ = BN / 32;     // B frags per wave
    constexpr int CA = BM / 16;     // A staging chunks
    constexpr int CB = BN / 16;
    __shared__ ushort Asm[2][BM * 32];
    __shared__ ushort Bsm[2][BN * 32];
    const int tid = threadIdx.x;
    const int w = tid >> 6, l = tid & 63;
    const int cpx = gridDim.x >> 3;
    const int wg = (blockIdx.x & 7) * cpx + (blockIdx.x >> 3);
    const int m0 = (wg / nbx) * BM, n0 = (wg % nbx) * BN;
    const int wr = w >> 1, wc = w & 1;
    const int lr = l & 15, g = l >> 4;

    const ushort* W_ = (!GROUP || m0 < Msplit) ? Wt : Wt2;
    const float* b_ = (!GROUP || m0 < Msplit) ? bias : bias2;

    f32x4 acc[MI][NJ] = {};
    const int nt = K >> 5;

    #define STAGE(buf, kt)                                                        \
        do {                                                                      \
            const int k0s = (kt) << 5;                                            \
            for (int c = w; c < CA; c += 4)                                       \
                gload16(&A[(size_t)(m0 + c * 16 + lr) * K + k0s + 8 * g],         \
                        &Asm[buf][c * 512]);                                      \
            for (int c = w; c < CB; c += 4)                                       \
                gload16(&W_[(size_t)(n0 + c * 16 + lr) * K + k0s + 8 * g],        \
                        &Bsm[buf][c * 512]);                                      \
        } while (0)

    STAGE(0, 0);
    __syncthreads();
    int cur = 0;
    for (int t = 0; t < nt; ++t) {
        if (t + 1 < nt) STAGE(cur ^ 1, t + 1);
        FragU af[MI], bf4[NJ];
        #pragma unroll
        for (int mi = 0; mi < MI; ++mi)
            af[mi].u4 = *reinterpret_cast<const uint4*>(
                &Asm[cur][(wr * MI + mi) * 512 + l * 8]);
        #pragma unroll
        for (int nj = 0; nj < NJ; ++nj)
            bf4[nj].u4 = *reinterpret_cast<const uint4*>(
                &Bsm[cur][(wc * NJ + nj) * 512 + l * 8]);
        #pragma unroll
        for (int mi = 0; mi < MI; ++mi)
            #pragma unroll
            for (int nj = 0; nj < NJ; ++nj)
                acc[mi][nj] = __builtin_amdgcn_mfma_f32_16x16x32_bf16(
                    af[mi].v, bf4[nj].v, acc[mi][nj], 0, 0, 0);
        __syncthreads();
        cur ^= 1;
    }
    #undef STAGE

    float alpha = 0.f, beta = 0.f;
    if (FINAL) { alpha = alphap[0]; beta = betap[0]; }
    #pragma unroll
    for (int mi = 0; mi < MI; ++mi) {
        #pragma unroll
        for (int r = 0; r < 4; ++r) {
            const int m = m0 + wr * (MI * 16) + mi * 16 + g * 4 + r;
            #pragma unroll
            for (int nj = 0; nj < NJ; ++nj) {
                const int n = n0 + wc * (NJ * 16) + nj * 16 + lr;
                const size_t idx = (size_t)m * Nn + n;
                float v = acc[mi][nj][r] + b_[n];
                if (ACT == 1) v = gelu_f(v);
                if (FINAL)
                    v = bf2f(fusedb[idx]) + alpha * v + beta * bf2f(resb[idx]);
                if (OUT == 0) ((float*)Cv)[idx] = v;
                else          ((ushort*)Cv)[idx] = f2bf(v);
            }
        }
    }
}

// ---------------------------------------------------------------------------
// weight convert+transpose: Wt[n][k] = bf16(W[k][n]); 8 weights via blockIdx.z
// ---------------------------------------------------------------------------
__global__ __launch_bounds__(256) void cvtw_k(
    const float* __restrict__ w0, const float* __restrict__ w1,
    const float* __restrict__ w2, const float* __restrict__ w3,
    const float* __restrict__ w4, const float* __restrict__ w5,
    const float* __restrict__ w6, const float* __restrict__ w7,
    ushort* __restrict__ dst)
{
    __shared__ ushort T[64][72];
    const int id = blockIdx.z;
    int K, Nn, off;
    const float* src;
    switch (id) {
        case 0: src = w0; K = 512;  Nn = 1536; off = WOFF_SQ;    break;
        case 1: src = w1; K = 512;  Nn = 1536; off = WOFF_PQ;    break;
        case 2: src = w2; K = 512;  Nn = 512;  off = WOFF_SPROJ; break;
        case 3: src = w3; K = 512;  Nn = 512;  off = WOFF_PPROJ; break;
        case 4: src = w4; K = 512;  Nn = 1024; off = WOFF_VF1;   break;
        case 5: src = w5; K = 1024; Nn = 512;  off = WOFF_VF2;   break;
        case 6: src = w6; K = 512;  Nn = 1024; off = WOFF_FR1;   break;
        default: src = w7; K = 1024; Nn = 512; off = WOFF_FR2;   break;
    }
    const int n0 = blockIdx.x * 64, k0 = blockIdx.y * 64;
    if (n0 >= Nn || k0 >= K) return;
    const int t = threadIdx.x;
    const int q = t >> 6, e = t & 63;
    #pragma unroll 4
    for (int i = 0; i < 16; ++i) {
        const int kl = q * 16 + i;
        T[e][kl] = f2bf(src[(size_t)(k0 + kl) * Nn + n0 + e]);
    }
    __syncthreads();
    #pragma unroll 4
    for (int i = 0; i < 16; ++i) {
        const int nl = q * 16 + i;
        dst[(size_t)off + (size_t)(n0 + nl) * K + k0 + e] = T[nl][e];
    }
}

// ---------------------------------------------------------------------------
// input convert: xh = bf16(h), xl = bf16(l), rb = bf16(0.5*(h+l)); 8/thread
// ---------------------------------------------------------------------------
__global__ __launch_bounds__(256) void cvt3_k(const float* __restrict__ h,
                                              const float* __restrict__ l,
                                              ushort* __restrict__ xh,
                                              ushort* __restrict__ xl,
                                              ushort* __restrict__ rb)
{
    const size_t i = ((size_t)blockIdx.x * 256 + threadIdx.x) * 8;
    const float4 h0 = *reinterpret_cast<const float4*>(h + i);
    const float4 h1 = *reinterpret_cast<const float4*>(h + i + 4);
    const float4 l0 = *reinterpret_cast<const float4*>(l + i);
    const float4 l1 = *reinterpret_cast<const float4*>(l + i + 4);
    FragU oh, ol, orr;
    oh.u[0] = pack2(h0.x, h0.y); oh.u[1] = pack2(h0.z, h0.w);
    oh.u[2] = pack2(h1.x, h1.y); oh.u[3] = pack2(h1.z, h1.w);
    ol.u[0] = pack2(l0.x, l0.y); ol.u[1] = pack2(l0.z, l0.w);
    ol.u[2] = pack2(l1.x, l1.y); ol.u[3] = pack2(l1.z, l1.w);
    orr.u[0] = pack2(0.5f * (h0.x + l0.x), 0.5f * (h0.y + l0.y));
    orr.u[1] = pack2(0.5f * (h0.z + l0.z), 0.5f * (h0.w + l0.w));
    orr.u[2] = pack2(0.5f * (h1.x + l1.x), 0.5f * (h1.y + l1.y));
    orr.u[3] = pack2(0.5f * (h1.z + l1.z), 0.5f * (h1.w + l1.w));
    *reinterpret_cast<uint4*>(xh + i) = oh.u4;
    *reinterpret_cast<uint4*>(xl + i) = ol.u4;
    *reinterpret_cast<uint4*>(rb + i) = orr.u4;
}

// ---------------------------------------------------------------------------
// Fused LN(1536) + head split + l2norm, bf16 in/out, both branches.
// VECTORIZED: lane l holds 8 contiguous elems per 512-chunk (q/k/v);
// per-head l2norm = 3-shuffle reduce over the aligned 8-lane group.
// ---------------------------------------------------------------------------
__global__ __launch_bounds__(256) void lnprep_k(ushort* __restrict__ x,
                                                const float* __restrict__ lng0,
                                                const float* __restrict__ lnb0,
                                                const float* __restrict__ lng1,
                                                const float* __restrict__ lnb1,
                                                const float* __restrict__ temp,
                                                ushort* __restrict__ Kb,
                                                ushort* __restrict__ Vt)
{
    __shared__ ushort Vs[8 * 512];
    const int w = threadIdx.x >> 6, l = threadIdx.x & 63;
    const int n0 = blockIdx.x * 8;
    const float L2E = 1.4426950408889634f;
    const float* lng = (n0 < 8192) ? lng0 : lng1;
    const float* lnb = (n0 < 8192) ? lnb0 : lnb1;
    const int hd8 = l >> 3;          // head for q/k chunks
    const int d8  = (l & 7) * 8;     // dim base within head
    const float tL = temp[hd8] * L2E;

    float gq[8], bq[8], gk[8], bk[8], gv[8], bv[8];
    #pragma unroll
    for (int e = 0; e < 8; ++e) {
        gq[e] = lng[8 * l + e];          bq[e] = lnb[8 * l + e];
        gk[e] = lng[512 + 8 * l + e];    bk[e] = lnb[512 + 8 * l + e];
        gv[e] = lng[1024 + 8 * l + e];   bv[e] = lnb[1024 + 8 * l + e];
    }

    #pragma unroll
    for (int rr = 0; rr < 2; ++rr) {
        const int row = n0 + w * 2 + rr;
        const int bb = row >> 10;        // 0..15
        const int n = row & 1023;
        ushort* xr = x + (size_t)row * D3_;
        FragU cq, ck, cv;
        cq.u4 = *reinterpret_cast<const uint4*>(xr + 8 * l);
        ck.u4 = *reinterpret_cast<const uint4*>(xr + 512 + 8 * l);
        cv.u4 = *reinterpret_cast<const uint4*>(xr + 1024 + 8 * l);
        float q[8], k[8], v[8];
        float s = 0.f, ss = 0.f;
        #pragma unroll
        for (int e = 0; e < 8; ++e) {
            q[e] = bf2f(cq.s[e]); k[e] = bf2f(ck.s[e]); v[e] = bf2f(cv.s[e]);
            s += q[e] + k[e] + v[e];
            ss += q[e] * q[e] + k[e] * k[e] + v[e] * v[e];
        }
        #pragma unroll
        for (int off = 32; off; off >>= 1) {
            s += __shfl_xor(s, off);
            ss += __shfl_xor(ss, off);
        }
        const float mu = s * (1.0f / D3_);
        const float var = ss * (1.0f / D3_) - mu * mu;
        const float rs = rsqrtf(var + 1e-5f);
        float sq = 0.f, sk = 0.f;
        #pragma unroll
        for (int e = 0; e < 8; ++e) {
            q[e] = (q[e] - mu) * rs * gq[e] + bq[e];
            k[e] = (k[e] - mu) * rs * gk[e] + bk[e];
            v[e] = (v[e] - mu) * rs * gv[e] + bv[e];
            sq += q[e] * q[e];
            sk += k[e] * k[e];
        }
        #pragma unroll
        for (int off = 4; off; off >>= 1) {
            sq += __shfl_xor(sq, off);
            sk += __shfl_xor(sk, off);
        }
        const float qs = tL / fmaxf(sqrtf(sq), 1e-12f);
        const float ks = 1.0f / fmaxf(sqrtf(sk), 1e-12f);
        FragU oq, ok, ov;
        #pragma unroll
        for (int e = 0; e < 8; ++e) {
            oq.s[e] = f2bf(q[e] * qs);
            ok.s[e] = f2bf(k[e] * ks);
            ov.s[e] = f2bf(v[e]);
        }
        *reinterpret_cast<uint4*>(xr + 8 * l) = oq.u4;   // Q in place
        *reinterpret_cast<uint4*>(
            &Kb[((size_t)(bb * 8 + hd8) * N_ + n) * HD_ + d8]) = ok.u4;
        *reinterpret_cast<uint4*>(&Vs[(w * 2 + rr) * 512 + 8 * l]) = ov.u4;
    }
    __syncthreads();
    const int bb = n0 >> 10;
    #pragma unroll
    for (int it = 0; it < 2; ++it) {
        const int combo = threadIdx.x + it * 256;   // h*64 + d
        FragU f;
        #pragma unroll
        for (int tok = 0; tok < 8; ++tok) f.s[tok] = Vs[tok * 512 + combo];
        *reinterpret_cast<uint4*>(
            &Vt[((size_t)(bb * 8 + (combo >> 6)) * HD_ + (combo & 63)) * N_ + (n0 & 1023)]) = f.u4;
    }
}

// ---------------------------------------------------------------------------
// Flash-style cosine attention, both branches. grid 1024, XCD-swizzled.
// Round-11 structure (best measured): double-buffered Ks/Vs LDS (one barrier
// per KV tile), setprio around MFMA cluster, softmax shift folded into MFMA
// C-init, lsum via ones-MFMA.
// ---------------------------------------------------------------------------
__global__ __launch_bounds__(256) void fattn_k(const ushort* __restrict__ Qu,
                                               const ushort* __restrict__ Kb,
                                               const ushort* __restrict__ Vt,
                                               const float* __restrict__ temp,
                                               ushort* __restrict__ out)
{
    __shared__ ushort Ks[2][64 * 72];
    __shared__ ushort Vs[2][64 * 72];
    const int tid = threadIdx.x;
    const int cpx = gridDim.x >> 3;
    const int wg = (blockIdx.x & 7) * cpx + (blockIdx.x >> 3);
    const int nb = wg & 7;
    const int h  = (wg >> 3) & 7;
    const int bb = wg >> 6;          // 0..15
    const int bh = bb * 8 + h;       // 0..127
    const int n0 = nb * 128;
    const int w  = tid >> 6;
    const int l  = tid & 63;
    const int lr = l & 15;
    const int g  = l >> 4;
    const float m2 = fabsf(temp[h]) * 1.4426950408889634f;
    const f32x4 mInit = {-m2, -m2, -m2, -m2};

    FragU ones;
    ones.u[0] = ones.u[1] = ones.u[2] = ones.u[3] = 0x3F803F80u;

    const int qb = n0 + w * 32;
    FragU qa0, qa1, qb0, qb1;
    {
        const size_t rb0 = (size_t)(bb * N_ + qb + lr) * D3_ + h * 64 + 8 * g;
        const size_t rb1 = (size_t)(bb * N_ + qb + 16 + lr) * D3_ + h * 64 + 8 * g;
        qa0.u4 = *reinterpret_cast<const uint4*>(&Qu[rb0]);
        qa1.u4 = *reinterpret_cast<const uint4*>(&Qu[rb0 + 32]);
        qb0.u4 = *reinterpret_cast<const uint4*>(&Qu[rb1]);
        qb1.u4 = *reinterpret_cast<const uint4*>(&Qu[rb1 + 32]);
    }

    f32x4 OA[4] = {};
    f32x4 OB[4] = {};
    f32x4 LSA = {0.f, 0.f, 0.f, 0.f};
    f32x4 LSB = {0.f, 0.f, 0.f, 0.f};

    const ushort* kbase = Kb + (size_t)bh * N_ * HD_;
    const ushort* vbase = Vt + (size_t)bh * HD_ * N_;
    const int sr = tid >> 3;
    const int sc = (tid & 7) * 8;
    uint4 k0r, k1r, v0r, v1r;

    #define LOADT(kt)                                                           \
        do {                                                                    \
            const ushort* ks_ = kbase + (size_t)((kt) * 64) * HD_;              \
            const ushort* vs_ = vbase + (kt) * 64;                              \
            k0r = *reinterpret_cast<const uint4*>(ks_ + sr * HD_ + sc);         \
            k1r = *reinterpret_cast<const uint4*>(ks_ + (sr + 32) * HD_ + sc);  \
            v0r = *reinterpret_cast<const uint4*>(vs_ + (size_t)sr * N_ + sc);  \
            v1r = *reinterpret_cast<const uint4*>(vs_ + (size_t)(sr + 32) * N_ + sc); \
        } while (0)
    #define WRITET(p)                                                           \
        do {                                                                    \
            *reinterpret_cast<uint4*>(&Ks[p][sr * 72 + sc]) = k0r;              \
            *reinterpret_cast<uint4*>(&Ks[p][(sr + 32) * 72 + sc]) = k1r;       \
            *reinterpret_cast<uint4*>(&Vs[p][sr * 72 + sc]) = v0r;              \
            *reinterpret_cast<uint4*>(&Vs[p][(sr + 32) * 72 + sc]) = v1r;       \
        } while (0)

    LOADT(0);
    WRITET(0);

    #pragma unroll 1
    for (int kt = 0; kt < 16; ++kt) {
        const int p = kt & 1;
        __syncthreads();               // buf p fully written; buf p^1 free
        if (kt < 15) LOADT(kt + 1);    // global->reg, overlaps compute

        unsigned paA[2][4], paB[2][4];
        #pragma unroll
        for (int j = 0; j < 4; ++j) {
            FragU ka, kc;
            ka.u4 = *reinterpret_cast<const uint4*>(&Ks[p][(j * 16 + lr) * 72 + 8 * g]);
            kc.u4 = *reinterpret_cast<const uint4*>(&Ks[p][(j * 16 + lr) * 72 + 32 + 8 * g]);
            f32x4 sA = mInit, sB = mInit;
            sA = __builtin_amdgcn_mfma_f32_16x16x32_bf16(ka.v, qa0.v, sA, 0, 0, 0);
            sA = __builtin_amdgcn_mfma_f32_16x16x32_bf16(kc.v, qa1.v, sA, 0, 0, 0);
            sB = __builtin_amdgcn_mfma_f32_16x16x32_bf16(ka.v, qb0.v, sB, 0, 0, 0);
            sB = __builtin_amdgcn_mfma_f32_16x16x32_bf16(kc.v, qb1.v, sB, 0, 0, 0);
            float pA[4], pB[4];
            #pragma unroll
            for (int r = 0; r < 4; ++r) {
                pA[r] = exp2_fast(sA[r]);
                pB[r] = exp2_fast(sB[r]);
            }
            paA[j >> 1][2 * (j & 1) + 0] = pack2(pA[0], pA[1]);
            paA[j >> 1][2 * (j & 1) + 1] = pack2(pA[2], pA[3]);
            paB[j >> 1][2 * (j & 1) + 0] = pack2(pB[0], pB[1]);
            paB[j >> 1][2 * (j & 1) + 1] = pack2(pB[2], pB[3]);
        }

        __builtin_amdgcn_s_setprio(1);
        #pragma unroll
        for (int ks = 0; ks < 2; ++ks) {
            FragU fa, fb2;
            fa.u[0] = paA[ks][0]; fa.u[1] = paA[ks][1];
            fa.u[2] = paA[ks][2]; fa.u[3] = paA[ks][3];
            fb2.u[0] = paB[ks][0]; fb2.u[1] = paB[ks][1];
            fb2.u[2] = paB[ks][2]; fb2.u[3] = paB[ks][3];
            LSA = __builtin_amdgcn_mfma_f32_16x16x32_bf16(fa.v, ones.v, LSA, 0, 0, 0);
            LSB = __builtin_amdgcn_mfma_f32_16x16x32_bf16(fb2.v, ones.v, LSB, 0, 0, 0);
            #pragma unroll
            for (int s4 = 0; s4 < 4; ++s4) {
                FragU vb;
                const int vi = (lr + 16 * s4) * 72 + ks * 32 + 4 * g;
                *reinterpret_cast<uint2*>(&vb.u[0]) =
                    *reinterpret_cast<const uint2*>(&Vs[p][vi]);
                *reinterpret_cast<uint2*>(&vb.u[2]) =
                    *reinterpret_cast<const uint2*>(&Vs[p][vi + 16]);
                OA[s4] = __builtin_amdgcn_mfma_f32_16x16x32_bf16(fa.v, vb.v, OA[s4], 0, 0, 0);
                OB[s4] = __builtin_amdgcn_mfma_f32_16x16x32_bf16(fb2.v, vb.v, OB[s4], 0, 0, 0);
            }
        }
        __builtin_amdgcn_s_setprio(0);

        if (kt < 15) WRITET(p ^ 1);    // other buffer: no wave reads it now
    }
    #undef LOADT
    #undef WRITET

    // LS D-layout: row (= q) is (lane>>4)*4 + r — exactly the rows this lane
    // stores below, so no cross-lane reduction is needed.
    ushort* outp = out + ((size_t)(bb * N_) + qb) * D_ + h * HD_;
    #pragma unroll
    for (int r = 0; r < 4; ++r) {
        const float iA = 1.0f / LSA[r];
        const float iB = 1.0f / LSB[r];
        ushort* rowA = outp + (size_t)(4 * g + r) * D_;
        ushort* rowB = outp + (size_t)(16 + 4 * g + r) * D_;
        #pragma unroll
        for (int s4 = 0; s4 < 4; ++s4) {
            rowA[s4 * 16 + lr] = f2bf(OA[s4][r] * iA);
            rowB[s4 * 16 + lr] = f2bf(OB[s4][r] * iB);
        }
    }
}

// ---------------------------------------------------------------------------
// Merged cvtadd + means: one pass over spec/spat computes
//   Sb = bf16(spec + spat)   AND   Gp column partial sums (32-row chunks).
// grid = B*32 = 256 blocks (b = blk>>5, ch = blk&31), 256 thr (2 cols each).
// ---------------------------------------------------------------------------
__global__ __launch_bounds__(256) void sums_k(const ushort* __restrict__ spec,
                                              const ushort* __restrict__ spat,
                                              ushort* __restrict__ Sb,
                                              float* __restrict__ Gp)
{
    const int b = blockIdx.x >> 5;
    const int ch = blockIdx.x & 31;
    const int n0 = ch * 32;
    const int d0 = threadIdx.x * 2;
    float s1a = 0.f, s1b = 0.f, s2a = 0.f, s2b = 0.f;
    #pragma unroll 4
    for (int n = 0; n < 32; ++n) {
        const size_t idx = ((size_t)(b * N_) + n0 + n) * D_ + d0;
        ushort u1[2], u2[2];
        *reinterpret_cast<unsigned*>(u1) = *reinterpret_cast<const unsigned*>(spec + idx);
        *reinterpret_cast<unsigned*>(u2) = *reinterpret_cast<const unsigned*>(spat + idx);
        const float a0 = bf2f(u1[0]), a1 = bf2f(u1[1]);
        const float c0 = bf2f(u2[0]), c1 = bf2f(u2[1]);
        s1a += a0; s1b += a1;
        s2a += c0; s2b += c1;
        ushort o[2];
        o[0] = f2bf(a0 + c0);
        o[1] = f2bf(a1 + c1);
        *reinterpret_cast<unsigned*>(Sb + idx) = *reinterpret_cast<unsigned*>(o);
    }
    float* gp = Gp + (size_t)blockIdx.x * 1024;
    gp[d0] = s1a; gp[d0 + 1] = s1b;
    gp[512 + d0] = s2a; gp[512 + d0 + 1] = s2b;
}

// ---------------------------------------------------------------------------
// Merged gate MLP: grid = 8 (one block per batch). Per block: mean-vec xs,
// 8x chunked GEMV into LDS yv, then LN + GELU + 512x3 GEMV + softmax.
// ---------------------------------------------------------------------------
__global__ __launch_bounds__(256) void gatef_k(
    const float* __restrict__ Gp, const float* __restrict__ w1,
    const float* __restrict__ b1, const float* __restrict__ lng,
    const float* __restrict__ lnb, const float* __restrict__ w2,
    const float* __restrict__ b2, float* __restrict__ gate)
{
    __shared__ float xs[1024];
    __shared__ float red[4][64];
    __shared__ float red4[4];
    __shared__ float yv[512];
    const int b = blockIdx.x, tid = threadIdx.x;
    for (int k = tid; k < 1024; k += 256) {
        float s = 0.f;
        #pragma unroll 8
        for (int c = 0; c < 32; ++c) s += Gp[(size_t)(b * 32 + c) * 1024 + k];
        xs[k] = s * (1.0f / N_);
    }
    __syncthreads();
    const int jl = tid & 63, seg = tid >> 6;
    for (int jc = 0; jc < 8; ++jc) {
        float acc = 0.f;
        const float* wp = w1 + (size_t)(seg * 256) * 512 + jc * 64 + jl;
        const float* xp = xs + seg * 256;
        #pragma unroll 8
        for (int k = 0; k < 256; ++k) acc += xp[k] * wp[(size_t)k * 512];
        red[seg][jl] = acc;
        __syncthreads();
        if (tid < 64)
            yv[jc * 64 + tid] = red[0][tid] + red[1][tid] + red[2][tid] +
                                red[3][tid] + b1[jc * 64 + tid];
        __syncthreads();
    }
    const float v0 = yv[tid];
    const float v1 = yv[256 + tid];
    const float s = blk_sum(v0 + v1, red4);
    const float ss = blk_sum(v0 * v0 + v1 * v1, red4);
    const float mu = s * (1.0f / 512.0f);
    const float var = ss * (1.0f / 512.0f) - mu * mu;
    const float rs = rsqrtf(var + 1e-5f);
    const float z0 = gelu_f((v0 - mu) * rs * lng[tid] + lnb[tid]);
    const float z1 = gelu_f((v1 - mu) * rs * lng[tid + 256] + lnb[tid + 256]);
    float p0 = z0 * w2[tid * 3 + 0] + z1 * w2[(tid + 256) * 3 + 0];
    float p1 = z0 * w2[tid * 3 + 1] + z1 * w2[(tid + 256) * 3 + 1];
    float p2 = z0 * w2[tid * 3 + 2] + z1 * w2[(tid + 256) * 3 + 2];
    p0 = blk_sum(p0, red4);
    p1 = blk_sum(p1, red4);
    p2 = blk_sum(p2, red4);
    if (tid == 0) {
        p0 += b2[0]; p1 += b2[1]; p2 += b2[2];
        const float m = fmaxf(p0, fmaxf(p1, p2));
        const float e0 = expf(p0 - m), e1 = expf(p1 - m), e2 = expf(p2 - m);
        const float inv = 1.0f / (e0 + e1 + e2);
        gate[b * 3 + 0] = e0 * inv;
        gate[b * 3 + 1] = e1 * inv;
        gate[b * 3 + 2] = e2 * inv;
    }
}

// ---------------------------------------------------------------------------
// fused = g0*spec + g1*spat + g2*vol (all bf16); writes bf16
// ---------------------------------------------------------------------------
__global__ __launch_bounds__(256) void fuse_k(
    const ushort* __restrict__ spec, const ushort* __restrict__ spat,
    const ushort* __restrict__ volb, const float* __restrict__ gate,
    ushort* __restrict__ fb)
{
    const size_t i4 = ((size_t)blockIdx.x * 256 + threadIdx.x) * 4;
    const int b = (int)(i4 >> 19);
    const float g0 = gate[b * 3 + 0], g1 = gate[b * 3 + 1], g2 = gate[b * 3 + 2];
    ushort au[4], cu[4], vu[4];
    *reinterpret_cast<uint2*>(au) = *reinterpret_cast<const uint2*>(spec + i4);
    *reinterpret_cast<uint2*>(cu) = *reinterpret_cast<const uint2*>(spat + i4);
    *reinterpret_cast<uint2*>(vu) = *reinterpret_cast<const uint2*>(volb + i4);
    union { ushort s[4]; uint2 u; } ob;
    #pragma unroll
    for (int e = 0; e < 4; ++e)
        ob.s[e] = f2bf(g0 * bf2f(au[e]) + g1 * bf2f(cu[e]) + g2 * bf2f(vu[e]));
    *reinterpret_cast<uint2*>(fb + i4) = ob.u;
}

// ---------------------------------------------------------------------------
extern "C" void kernel_launch(void* const* d_in, const int* in_sizes, int n_in,
                              void* d_out, int out_size, void* d_ws, size_t ws_size,
                              hipStream_t stream)
{
    const float* hsi    = (const float*)d_in[0];
    const float* lidar  = (const float*)d_in[1];
    const float* temp   = (const float*)d_in[2];
    const float* sq_w   = (const float*)d_in[3];
    const float* sq_b   = (const float*)d_in[4];
    const float* sq_lng = (const float*)d_in[5];
    const float* sq_lnb = (const float*)d_in[6];
    const float* sproj_w = (const float*)d_in[7];
    const float* sproj_b = (const float*)d_in[8];
    const float* pq_w   = (const float*)d_in[9];
    const float* pq_b   = (const float*)d_in[10];
    const float* pq_lng = (const float*)d_in[11];
    const float* pq_lnb = (const float*)d_in[12];
    const float* pproj_w = (const float*)d_in[13];
    const float* pproj_b = (const float*)d_in[14];
    const float* vf_w1  = (const float*)d_in[15];
    const float* vf_b1  = (const float*)d_in[16];
    const float* vf_w2  = (const float*)d_in[17];
    const float* vf_b2  = (const float*)d_in[18];
    const float* ag_w1  = (const float*)d_in[19];
    const float* ag_b1  = (const float*)d_in[20];
    const float* ag_lng = (const float*)d_in[21];
    const float* ag_lnb = (const float*)d_in[22];
    const float* ag_w2  = (const float*)d_in[23];
    const float* ag_b2  = (const float*)d_in[24];
    const float* fr_w1  = (const float*)d_in[25];
    const float* fr_b1  = (const float*)d_in[26];
    const float* fr_w2  = (const float*)d_in[27];
    const float* fr_b2  = (const float*)d_in[28];
    const float* alpha  = (const float*)d_in[29];
    const float* beta   = (const float*)d_in[30];
    float* out = (float*)d_out;

    // ---- workspace layout (ushort units; peak ~117.4 MB) ----
    ushort* base = (ushort*)d_ws;
    ushort* Qkv  = base;                 // [16384][1536] bf16 (50.3 MB), qkv+Q
    ushort* Ob   = base;                 //   after attn: [16384][512] proj out
    ushort* Sb   = base + 8388608;       //   [8192][512] spec+spat bf16
    ushort* volb = base + 12582912;      //   [8192][512] volumetric bf16
    ushort* fb   = base + 16777216;      //   [8192][512] fused bf16
    float*  Gp   = (float*)(base + 20971520);  // [256][1024] f32 partials
    float*  gate = Gp + 262144;
    ushort* Kb   = base + 25165824;      // [128][1024][64] bf16 (16.8 MB)
    ushort* Vt   = base + 33554432;      // [128][64][1024] bf16 (16.8 MB)
    ushort* Hb   = base + 25165824;      //   after attn: [8192][1024] MLP hidden
    ushort* Ab   = base + 41943040;      // [16384][512] attn out bf16 (16.8 MB)
    ushort* Xb   = base + 41943040;      //   (pre-attn) [16384][512] bf16 inputs
    ushort* Wb   = base + 50331648;      // bf16 weights pool (8.4 MB)
    ushort* Rb   = base + 54525952;      // [8192][512] bf16 0.5*(hsi+lidar)

    const dim3 blk(256);

    // ---- weight + input conversion (Rb = 0.5*(hsi+lidar) for final residual)
    cvtw_k<<<dim3(24, 16, 8), blk, 0, stream>>>(sq_w, pq_w, sproj_w, pproj_w,
                                                vf_w1, vf_w2, fr_w1, fr_w2, Wb);
    cvt3_k<<<2048, blk, 0, stream>>>(hsi, lidar, Xb, Xb + (size_t)M_ * D_, Rb);

    // ---- qkv for BOTH branches (grouped, 128x128 tile — proven best)
    pgemm_k<128,128,0,1,false,true><<<1536, blk, 0, stream>>>(
        Xb, Wb + WOFF_SQ, Wb + WOFF_PQ, sq_b, pq_b, M_,
        Qkv, 12, D3_, D_, nullptr, nullptr, nullptr, nullptr);

    // ---- LN + l2norm + K/V prep, both branches (vectorized)
    lnprep_k<<<2048, blk, 0, stream>>>(Qkv, sq_lng, sq_lnb, pq_lng, pq_lnb,
                                       temp, Kb, Vt);

    // ---- attention, both branches
    fattn_k<<<1024, blk, 0, stream>>>(Qkv, Kb, Vt, temp, Ab);

    // ---- projection for BOTH branches (grouped) -> Ob bf16
    pgemm_k<128,64,0,1,false,true><<<1024, blk, 0, stream>>>(
        Ab, Wb + WOFF_SPROJ, Wb + WOFF_PPROJ, sproj_b, pproj_b, M_,
        Ob, 8, D_, D_, nullptr, nullptr, nullptr, nullptr);

    const ushort* spec_b = Ob;
    const ushort* spat_b = Ob + (size_t)M_ * D_;

    // ---- one pass: Sb = spec+spat AND gate column partials; then gate MLP
    sums_k<<<256, blk, 0, stream>>>(spec_b, spat_b, Sb, Gp);
    gatef_k<<<B_, blk, 0, stream>>>(Gp, ag_w1, ag_b1, ag_lng, ag_lnb,
                                    ag_w2, ag_b2, gate);

    // ---- volumetric MLP: Hb = gelu(Sb@vf_w1); volb = Hb@vf_w2
    pgemm_k<128,64,1,1,false,false><<<1024, blk, 0, stream>>>(
        Sb, Wb + WOFF_VF1, nullptr, vf_b1, nullptr, 0,
        Hb, 16, 1024, D_, nullptr, nullptr, nullptr, nullptr);
    pgemm_k<128,64,0,1,false,false><<<512, blk, 0, stream>>>(
        Hb, Wb + WOFF_VF2, nullptr, vf_b2, nullptr, 0,
        volb, 8, D_, 1024, nullptr, nullptr, nullptr, nullptr);

    // ---- fuse + recal MLP + final combine
    fuse_k<<<4096, blk, 0, stream>>>(spec_b, spat_b, volb, gate, fb);
    pgemm_k<128,64,1,1,false,false><<<1024, blk, 0, stream>>>(
        fb, Wb + WOFF_FR1, nullptr, fr_b1, nullptr, 0,
        Hb, 16, 1024, D_, nullptr, nullptr, nullptr, nullptr);
    pgemm_k<128,64,0,0,true,false><<<512, blk, 0, stream>>>(
        Hb, Wb + WOFF_FR2, nullptr, fr_b2, nullptr, 0,
        out, 8, D_, 1024, fb, Rb, alpha, beta);
}

// Round 16
// 327.515 us; speedup vs baseline: 1.2547x; 1.2547x over previous
//
#include <hip/hip_runtime.h>
#include <hip/hip_bf16.h>
#include <math.h>

#define B_   8
#define N_   1024
#define D_   512
#define H_   8
#define HD_  64
#define D3_  1536
#define M_   (B_ * N_)   // 8192 tokens per branch; 16384 combined

// bf16 weight-pool offsets (elements)
#define WOFF_SQ    0
#define WOFF_PQ    786432
#define WOFF_SPROJ 1572864
#define WOFF_PPROJ 1835008
#define WOFF_VF1   2097152
#define WOFF_VF2   2621440
#define WOFF_FR1   3145728
#define WOFF_FR2   3670016

typedef float f32x4 __attribute__((ext_vector_type(4)));
typedef __bf16 bf16x8 __attribute__((ext_vector_type(8)));

union FragU {
    uint4 u4;
    unsigned int u[4];
    ushort s[8];
    bf16x8 v;
};

static __device__ __forceinline__ ushort f2bf(float x) {
    union { __bf16 h; ushort u; } c;
    c.h = (__bf16)x;
    return c.u;
}

static __device__ __forceinline__ float bf2f(ushort u) {
    union { unsigned u; float f; } c;
    c.u = ((unsigned)u) << 16;
    return c.f;
}

static __device__ __forceinline__ unsigned int pack2(float a, float b) {
    return (unsigned int)f2bf(a) | ((unsigned int)f2bf(b) << 16);
}

static __device__ __forceinline__ float gelu_f(float x) {
    return 0.5f * x * (1.0f + erff(x * 0.7071067811865475f));
}

#if __has_builtin(__builtin_amdgcn_exp2f)
static __device__ __forceinline__ float exp2_fast(float x) { return __builtin_amdgcn_exp2f(x); }
#else
static __device__ __forceinline__ float exp2_fast(float x) { return exp2f(x); }
#endif

// async global->LDS, 16B per lane; lds base must be wave-uniform
static __device__ __forceinline__ void gload16(const ushort* g, ushort* lds) {
    __builtin_amdgcn_global_load_lds(
        (const __attribute__((address_space(1))) void*)g,
        (__attribute__((address_space(3))) void*)lds, 16, 0, 0);
}

// block-wide sum, blockDim.x == 256 (4 waves)
static __device__ __forceinline__ float blk_sum(float v, float* red) {
    #pragma unroll
    for (int off = 32; off; off >>= 1) v += __shfl_xor(v, off);
    const int w = threadIdx.x >> 6;
    __syncthreads();
    if ((threadIdx.x & 63) == 0) red[w] = v;
    __syncthreads();
    return red[0] + red[1] + red[2] + red[3];
}

// ---------------------------------------------------------------------------
// bf16 MFMA GEMM (BK=32, fragment-major LDS, global_load_lds, 2-phase
// prefetch). Templated BMxBN tile, 4 waves.
// GROUP: rows >= Msplit use Wt2/bias2 (two-branch batched GEMM).
// OUT: 0 = f32; 1 = bf16.  ACT: 1 = exact GELU.
// FINAL: C = bf2f(fusedb) + alpha*(acc+bias) + beta*bf2f(resb)   (f32 out)
// XCD-chunked swizzle (grid % 8 == 0), m-major block order.
// ---------------------------------------------------------------------------
template <int BM, int BN, int ACT, int OUT, bool FINAL, bool GROUP>
__global__ __launch_bounds__(256) void pgemm_k(
    const ushort* __restrict__ A, const ushort* __restrict__ Wt,
    const ushort* __restrict__ Wt2, const float* __restrict__ bias,
    const float* __restrict__ bias2, int Msplit,
    void* __restrict__ Cv, int nbx, int Nn, int K,
    const ushort* __restrict__ fusedb, const ushort* __restrict__ resb,
    const float* __restrict__ alphap, const float* __restrict__ betap)
{
    constexpr int MI = BM / 32;     // A frags per wave
    constexpr int NJ = BN / 32;     // B frags per wave
    constexpr int CA = BM / 16;     // A staging chunks
    constexpr int CB = BN / 16;
    __shared__ ushort Asm[2][BM * 32];
    __shared__ ushort Bsm[2][BN * 32];
    const int tid = threadIdx.x;
    const int w = tid >> 6, l = tid & 63;
    const int cpx = gridDim.x >> 3;
    const int wg = (blockIdx.x & 7) * cpx + (blockIdx.x >> 3);
    const int m0 = (wg / nbx) * BM, n0 = (wg % nbx) * BN;
    const int wr = w >> 1, wc = w & 1;
    const int lr = l & 15, g = l >> 4;

    const ushort* W_ = (!GROUP || m0 < Msplit) ? Wt : Wt2;
    const float* b_ = (!GROUP || m0 < Msplit) ? bias : bias2;

    f32x4 acc[MI][NJ] = {};
    const int nt = K >> 5;

    #define STAGE(buf, kt)                                                        \
        do {                                                                      \
            const int k0s = (kt) << 5;                                            \
            for (int c = w; c < CA; c += 4)                                       \
                gload16(&A[(size_t)(m0 + c * 16 + lr) * K + k0s + 8 * g],         \
                        &Asm[buf][c * 512]);                                      \
            for (int c = w; c < CB; c += 4)                                       \
                gload16(&W_[(size_t)(n0 + c * 16 + lr) * K + k0s + 8 * g],        \
                        &Bsm[buf][c * 512]);                                      \
        } while (0)

    STAGE(0, 0);
    __syncthreads();
    int cur = 0;
    for (int t = 0; t < nt; ++t) {
        if (t + 1 < nt) STAGE(cur ^ 1, t + 1);
        FragU af[MI], bf4[NJ];
        #pragma unroll
        for (int mi = 0; mi < MI; ++mi)
            af[mi].u4 = *reinterpret_cast<const uint4*>(
                &Asm[cur][(wr * MI + mi) * 512 + l * 8]);
        #pragma unroll
        for (int nj = 0; nj < NJ; ++nj)
            bf4[nj].u4 = *reinterpret_cast<const uint4*>(
                &Bsm[cur][(wc * NJ + nj) * 512 + l * 8]);
        #pragma unroll
        for (int mi = 0; mi < MI; ++mi)
            #pragma unroll
            for (int nj = 0; nj < NJ; ++nj)
                acc[mi][nj] = __builtin_amdgcn_mfma_f32_16x16x32_bf16(
                    af[mi].v, bf4[nj].v, acc[mi][nj], 0, 0, 0);
        __syncthreads();
        cur ^= 1;
    }
    #undef STAGE

    float alpha = 0.f, beta = 0.f;
    if (FINAL) { alpha = alphap[0]; beta = betap[0]; }
    #pragma unroll
    for (int mi = 0; mi < MI; ++mi) {
        #pragma unroll
        for (int r = 0; r < 4; ++r) {
            const int m = m0 + wr * (MI * 16) + mi * 16 + g * 4 + r;
            #pragma unroll
            for (int nj = 0; nj < NJ; ++nj) {
                const int n = n0 + wc * (NJ * 16) + nj * 16 + lr;
                const size_t idx = (size_t)m * Nn + n;
                float v = acc[mi][nj][r] + b_[n];
                if (ACT == 1) v = gelu_f(v);
                if (FINAL)
                    v = bf2f(fusedb[idx]) + alpha * v + beta * bf2f(resb[idx]);
                if (OUT == 0) ((float*)Cv)[idx] = v;
                else          ((ushort*)Cv)[idx] = f2bf(v);
            }
        }
    }
}

// ---------------------------------------------------------------------------
// weight convert+transpose: Wt[n][k] = bf16(W[k][n]); 8 weights via blockIdx.z
// ---------------------------------------------------------------------------
__global__ __launch_bounds__(256) void cvtw_k(
    const float* __restrict__ w0, const float* __restrict__ w1,
    const float* __restrict__ w2, const float* __restrict__ w3,
    const float* __restrict__ w4, const float* __restrict__ w5,
    const float* __restrict__ w6, const float* __restrict__ w7,
    ushort* __restrict__ dst)
{
    __shared__ ushort T[64][72];
    const int id = blockIdx.z;
    int K, Nn, off;
    const float* src;
    switch (id) {
        case 0: src = w0; K = 512;  Nn = 1536; off = WOFF_SQ;    break;
        case 1: src = w1; K = 512;  Nn = 1536; off = WOFF_PQ;    break;
        case 2: src = w2; K = 512;  Nn = 512;  off = WOFF_SPROJ; break;
        case 3: src = w3; K = 512;  Nn = 512;  off = WOFF_PPROJ; break;
        case 4: src = w4; K = 512;  Nn = 1024; off = WOFF_VF1;   break;
        case 5: src = w5; K = 1024; Nn = 512;  off = WOFF_VF2;   break;
        case 6: src = w6; K = 512;  Nn = 1024; off = WOFF_FR1;   break;
        default: src = w7; K = 1024; Nn = 512; off = WOFF_FR2;   break;
    }
    const int n0 = blockIdx.x * 64, k0 = blockIdx.y * 64;
    if (n0 >= Nn || k0 >= K) return;
    const int t = threadIdx.x;
    const int q = t >> 6, e = t & 63;
    #pragma unroll 4
    for (int i = 0; i < 16; ++i) {
        const int kl = q * 16 + i;
        T[e][kl] = f2bf(src[(size_t)(k0 + kl) * Nn + n0 + e]);
    }
    __syncthreads();
    #pragma unroll 4
    for (int i = 0; i < 16; ++i) {
        const int nl = q * 16 + i;
        dst[(size_t)off + (size_t)(n0 + nl) * K + k0 + e] = T[nl][e];
    }
}

// ---------------------------------------------------------------------------
// input convert: xh = bf16(h), xl = bf16(l), rb = bf16(0.5*(h+l)); 8/thread
// ---------------------------------------------------------------------------
__global__ __launch_bounds__(256) void cvt3_k(const float* __restrict__ h,
                                              const float* __restrict__ l,
                                              ushort* __restrict__ xh,
                                              ushort* __restrict__ xl,
                                              ushort* __restrict__ rb)
{
    const size_t i = ((size_t)blockIdx.x * 256 + threadIdx.x) * 8;
    const float4 h0 = *reinterpret_cast<const float4*>(h + i);
    const float4 h1 = *reinterpret_cast<const float4*>(h + i + 4);
    const float4 l0 = *reinterpret_cast<const float4*>(l + i);
    const float4 l1 = *reinterpret_cast<const float4*>(l + i + 4);
    FragU oh, ol, orr;
    oh.u[0] = pack2(h0.x, h0.y); oh.u[1] = pack2(h0.z, h0.w);
    oh.u[2] = pack2(h1.x, h1.y); oh.u[3] = pack2(h1.z, h1.w);
    ol.u[0] = pack2(l0.x, l0.y); ol.u[1] = pack2(l0.z, l0.w);
    ol.u[2] = pack2(l1.x, l1.y); ol.u[3] = pack2(l1.z, l1.w);
    orr.u[0] = pack2(0.5f * (h0.x + l0.x), 0.5f * (h0.y + l0.y));
    orr.u[1] = pack2(0.5f * (h0.z + l0.z), 0.5f * (h0.w + l0.w));
    orr.u[2] = pack2(0.5f * (h1.x + l1.x), 0.5f * (h1.y + l1.y));
    orr.u[3] = pack2(0.5f * (h1.z + l1.z), 0.5f * (h1.w + l1.w));
    *reinterpret_cast<uint4*>(xh + i) = oh.u4;
    *reinterpret_cast<uint4*>(xl + i) = ol.u4;
    *reinterpret_cast<uint4*>(rb + i) = orr.u4;
}

// ---------------------------------------------------------------------------
// Fused LN(1536) + head split + l2norm, bf16 in/out, both branches.
// VECTORIZED: lane l holds 8 contiguous elems per 512-chunk (q/k/v);
// per-head l2norm = 3-shuffle reduce over the aligned 8-lane group.
// ---------------------------------------------------------------------------
__global__ __launch_bounds__(256) void lnprep_k(ushort* __restrict__ x,
                                                const float* __restrict__ lng0,
                                                const float* __restrict__ lnb0,
                                                const float* __restrict__ lng1,
                                                const float* __restrict__ lnb1,
                                                const float* __restrict__ temp,
                                                ushort* __restrict__ Kb,
                                                ushort* __restrict__ Vt)
{
    __shared__ ushort Vs[8 * 512];
    const int w = threadIdx.x >> 6, l = threadIdx.x & 63;
    const int n0 = blockIdx.x * 8;
    const float L2E = 1.4426950408889634f;
    const float* lng = (n0 < 8192) ? lng0 : lng1;
    const float* lnb = (n0 < 8192) ? lnb0 : lnb1;
    const int hd8 = l >> 3;          // head for q/k chunks
    const int d8  = (l & 7) * 8;     // dim base within head
    const float tL = temp[hd8] * L2E;

    float gq[8], bq[8], gk[8], bk[8], gv[8], bv[8];
    #pragma unroll
    for (int e = 0; e < 8; ++e) {
        gq[e] = lng[8 * l + e];          bq[e] = lnb[8 * l + e];
        gk[e] = lng[512 + 8 * l + e];    bk[e] = lnb[512 + 8 * l + e];
        gv[e] = lng[1024 + 8 * l + e];   bv[e] = lnb[1024 + 8 * l + e];
    }

    #pragma unroll
    for (int rr = 0; rr < 2; ++rr) {
        const int row = n0 + w * 2 + rr;
        const int bb = row >> 10;        // 0..15
        const int n = row & 1023;
        ushort* xr = x + (size_t)row * D3_;
        FragU cq, ck, cv;
        cq.u4 = *reinterpret_cast<const uint4*>(xr + 8 * l);
        ck.u4 = *reinterpret_cast<const uint4*>(xr + 512 + 8 * l);
        cv.u4 = *reinterpret_cast<const uint4*>(xr + 1024 + 8 * l);
        float q[8], k[8], v[8];
        float s = 0.f, ss = 0.f;
        #pragma unroll
        for (int e = 0; e < 8; ++e) {
            q[e] = bf2f(cq.s[e]); k[e] = bf2f(ck.s[e]); v[e] = bf2f(cv.s[e]);
            s += q[e] + k[e] + v[e];
            ss += q[e] * q[e] + k[e] * k[e] + v[e] * v[e];
        }
        #pragma unroll
        for (int off = 32; off; off >>= 1) {
            s += __shfl_xor(s, off);
            ss += __shfl_xor(ss, off);
        }
        const float mu = s * (1.0f / D3_);
        const float var = ss * (1.0f / D3_) - mu * mu;
        const float rs = rsqrtf(var + 1e-5f);
        float sq = 0.f, sk = 0.f;
        #pragma unroll
        for (int e = 0; e < 8; ++e) {
            q[e] = (q[e] - mu) * rs * gq[e] + bq[e];
            k[e] = (k[e] - mu) * rs * gk[e] + bk[e];
            v[e] = (v[e] - mu) * rs * gv[e] + bv[e];
            sq += q[e] * q[e];
            sk += k[e] * k[e];
        }
        #pragma unroll
        for (int off = 4; off; off >>= 1) {
            sq += __shfl_xor(sq, off);
            sk += __shfl_xor(sk, off);
        }
        const float qs = tL / fmaxf(sqrtf(sq), 1e-12f);
        const float ks = 1.0f / fmaxf(sqrtf(sk), 1e-12f);
        FragU oq, ok, ov;
        #pragma unroll
        for (int e = 0; e < 8; ++e) {
            oq.s[e] = f2bf(q[e] * qs);
            ok.s[e] = f2bf(k[e] * ks);
            ov.s[e] = f2bf(v[e]);
        }
        *reinterpret_cast<uint4*>(xr + 8 * l) = oq.u4;   // Q in place
        *reinterpret_cast<uint4*>(
            &Kb[((size_t)(bb * 8 + hd8) * N_ + n) * HD_ + d8]) = ok.u4;
        *reinterpret_cast<uint4*>(&Vs[(w * 2 + rr) * 512 + 8 * l]) = ov.u4;
    }
    __syncthreads();
    const int bb = n0 >> 10;
    #pragma unroll
    for (int it = 0; it < 2; ++it) {
        const int combo = threadIdx.x + it * 256;   // h*64 + d
        FragU f;
        #pragma unroll
        for (int tok = 0; tok < 8; ++tok) f.s[tok] = Vs[tok * 512 + combo];
        *reinterpret_cast<uint4*>(
            &Vt[((size_t)(bb * 8 + (combo >> 6)) * HD_ + (combo & 63)) * N_ + (n0 & 1023)]) = f.u4;
    }
}

// ---------------------------------------------------------------------------
// Flash-style cosine attention, both branches. grid 1024, XCD-swizzled.
// Round-11 structure (best measured): double-buffered Ks/Vs LDS (one barrier
// per KV tile), setprio around MFMA cluster, softmax shift folded into MFMA
// C-init, lsum via ones-MFMA.
// ---------------------------------------------------------------------------
__global__ __launch_bounds__(256) void fattn_k(const ushort* __restrict__ Qu,
                                               const ushort* __restrict__ Kb,
                                               const ushort* __restrict__ Vt,
                                               const float* __restrict__ temp,
                                               ushort* __restrict__ out)
{
    __shared__ ushort Ks[2][64 * 72];
    __shared__ ushort Vs[2][64 * 72];
    const int tid = threadIdx.x;
    const int cpx = gridDim.x >> 3;
    const int wg = (blockIdx.x & 7) * cpx + (blockIdx.x >> 3);
    const int nb = wg & 7;
    const int h  = (wg >> 3) & 7;
    const int bb = wg >> 6;          // 0..15
    const int bh = bb * 8 + h;       // 0..127
    const int n0 = nb * 128;
    const int w  = tid >> 6;
    const int l  = tid & 63;
    const int lr = l & 15;
    const int g  = l >> 4;
    const float m2 = fabsf(temp[h]) * 1.4426950408889634f;
    const f32x4 mInit = {-m2, -m2, -m2, -m2};

    FragU ones;
    ones.u[0] = ones.u[1] = ones.u[2] = ones.u[3] = 0x3F803F80u;

    const int qb = n0 + w * 32;
    FragU qa0, qa1, qb0, qb1;
    {
        const size_t rb0 = (size_t)(bb * N_ + qb + lr) * D3_ + h * 64 + 8 * g;
        const size_t rb1 = (size_t)(bb * N_ + qb + 16 + lr) * D3_ + h * 64 + 8 * g;
        qa0.u4 = *reinterpret_cast<const uint4*>(&Qu[rb0]);
        qa1.u4 = *reinterpret_cast<const uint4*>(&Qu[rb0 + 32]);
        qb0.u4 = *reinterpret_cast<const uint4*>(&Qu[rb1]);
        qb1.u4 = *reinterpret_cast<const uint4*>(&Qu[rb1 + 32]);
    }

    f32x4 OA[4] = {};
    f32x4 OB[4] = {};
    f32x4 LSA = {0.f, 0.f, 0.f, 0.f};
    f32x4 LSB = {0.f, 0.f, 0.f, 0.f};

    const ushort* kbase = Kb + (size_t)bh * N_ * HD_;
    const ushort* vbase = Vt + (size_t)bh * HD_ * N_;
    const int sr = tid >> 3;
    const int sc = (tid & 7) * 8;
    uint4 k0r, k1r, v0r, v1r;

    #define LOADT(kt)                                                           \
        do {                                                                    \
            const ushort* ks_ = kbase + (size_t)((kt) * 64) * HD_;              \
            const ushort* vs_ = vbase + (kt) * 64;                              \
            k0r = *reinterpret_cast<const uint4*>(ks_ + sr * HD_ + sc);         \
            k1r = *reinterpret_cast<const uint4*>(ks_ + (sr + 32) * HD_ + sc);  \
            v0r = *reinterpret_cast<const uint4*>(vs_ + (size_t)sr * N_ + sc);  \
            v1r = *reinterpret_cast<const uint4*>(vs_ + (size_t)(sr + 32) * N_ + sc); \
        } while (0)
    #define WRITET(p)                                                           \
        do {                                                                    \
            *reinterpret_cast<uint4*>(&Ks[p][sr * 72 + sc]) = k0r;              \
            *reinterpret_cast<uint4*>(&Ks[p][(sr + 32) * 72 + sc]) = k1r;       \
            *reinterpret_cast<uint4*>(&Vs[p][sr * 72 + sc]) = v0r;              \
            *reinterpret_cast<uint4*>(&Vs[p][(sr + 32) * 72 + sc]) = v1r;       \
        } while (0)

    LOADT(0);
    WRITET(0);

    #pragma unroll 1
    for (int kt = 0; kt < 16; ++kt) {
        const int p = kt & 1;
        __syncthreads();               // buf p fully written; buf p^1 free
        if (kt < 15) LOADT(kt + 1);    // global->reg, overlaps compute

        unsigned paA[2][4], paB[2][4];
        #pragma unroll
        for (int j = 0; j < 4; ++j) {
            FragU ka, kc;
            ka.u4 = *reinterpret_cast<const uint4*>(&Ks[p][(j * 16 + lr) * 72 + 8 * g]);
            kc.u4 = *reinterpret_cast<const uint4*>(&Ks[p][(j * 16 + lr) * 72 + 32 + 8 * g]);
            f32x4 sA = mInit, sB = mInit;
            sA = __builtin_amdgcn_mfma_f32_16x16x32_bf16(ka.v, qa0.v, sA, 0, 0, 0);
            sA = __builtin_amdgcn_mfma_f32_16x16x32_bf16(kc.v, qa1.v, sA, 0, 0, 0);
            sB = __builtin_amdgcn_mfma_f32_16x16x32_bf16(ka.v, qb0.v, sB, 0, 0, 0);
            sB = __builtin_amdgcn_mfma_f32_16x16x32_bf16(kc.v, qb1.v, sB, 0, 0, 0);
            float pA[4], pB[4];
            #pragma unroll
            for (int r = 0; r < 4; ++r) {
                pA[r] = exp2_fast(sA[r]);
                pB[r] = exp2_fast(sB[r]);
            }
            paA[j >> 1][2 * (j & 1) + 0] = pack2(pA[0], pA[1]);
            paA[j >> 1][2 * (j & 1) + 1] = pack2(pA[2], pA[3]);
            paB[j >> 1][2 * (j & 1) + 0] = pack2(pB[0], pB[1]);
            paB[j >> 1][2 * (j & 1) + 1] = pack2(pB[2], pB[3]);
        }

        __builtin_amdgcn_s_setprio(1);
        #pragma unroll
        for (int ks = 0; ks < 2; ++ks) {
            FragU fa, fb2;
            fa.u[0] = paA[ks][0]; fa.u[1] = paA[ks][1];
            fa.u[2] = paA[ks][2]; fa.u[3] = paA[ks][3];
            fb2.u[0] = paB[ks][0]; fb2.u[1] = paB[ks][1];
            fb2.u[2] = paB[ks][2]; fb2.u[3] = paB[ks][3];
            LSA = __builtin_amdgcn_mfma_f32_16x16x32_bf16(fa.v, ones.v, LSA, 0, 0, 0);
            LSB = __builtin_amdgcn_mfma_f32_16x16x32_bf16(fb2.v, ones.v, LSB, 0, 0, 0);
            #pragma unroll
            for (int s4 = 0; s4 < 4; ++s4) {
                FragU vb;
                const int vi = (lr + 16 * s4) * 72 + ks * 32 + 4 * g;
                *reinterpret_cast<uint2*>(&vb.u[0]) =
                    *reinterpret_cast<const uint2*>(&Vs[p][vi]);
                *reinterpret_cast<uint2*>(&vb.u[2]) =
                    *reinterpret_cast<const uint2*>(&Vs[p][vi + 16]);
                OA[s4] = __builtin_amdgcn_mfma_f32_16x16x32_bf16(fa.v, vb.v, OA[s4], 0, 0, 0);
                OB[s4] = __builtin_amdgcn_mfma_f32_16x16x32_bf16(fb2.v, vb.v, OB[s4], 0, 0, 0);
            }
        }
        __builtin_amdgcn_s_setprio(0);

        if (kt < 15) WRITET(p ^ 1);    // other buffer: no wave reads it now
    }
    #undef LOADT
    #undef WRITET

    // LS D-layout: row (= q) is (lane>>4)*4 + r — exactly the rows this lane
    // stores below, so no cross-lane reduction is needed.
    ushort* outp = out + ((size_t)(bb * N_) + qb) * D_ + h * HD_;
    #pragma unroll
    for (int r = 0; r < 4; ++r) {
        const float iA = 1.0f / LSA[r];
        const float iB = 1.0f / LSB[r];
        ushort* rowA = outp + (size_t)(4 * g + r) * D_;
        ushort* rowB = outp + (size_t)(16 + 4 * g + r) * D_;
        #pragma unroll
        for (int s4 = 0; s4 < 4; ++s4) {
            rowA[s4 * 16 + lr] = f2bf(OA[s4][r] * iA);
            rowB[s4 * 16 + lr] = f2bf(OB[s4][r] * iB);
        }
    }
}

// ---------------------------------------------------------------------------
// Merged cvtadd + means: one pass over spec/spat computes
//   Sb = bf16(spec + spat)   AND   Gp column partial sums (32-row chunks).
// grid = B*32 = 256 blocks, 256 thr (2 cols each).
// ---------------------------------------------------------------------------
__global__ __launch_bounds__(256) void sums_k(const ushort* __restrict__ spec,
                                              const ushort* __restrict__ spat,
                                              ushort* __restrict__ Sb,
                                              float* __restrict__ Gp)
{
    const int b = blockIdx.x >> 5;
    const int ch = blockIdx.x & 31;
    const int n0 = ch * 32;
    const int d0 = threadIdx.x * 2;
    float s1a = 0.f, s1b = 0.f, s2a = 0.f, s2b = 0.f;
    #pragma unroll 4
    for (int n = 0; n < 32; ++n) {
        const size_t idx = ((size_t)(b * N_) + n0 + n) * D_ + d0;
        ushort u1[2], u2[2];
        *reinterpret_cast<unsigned*>(u1) = *reinterpret_cast<const unsigned*>(spec + idx);
        *reinterpret_cast<unsigned*>(u2) = *reinterpret_cast<const unsigned*>(spat + idx);
        const float a0 = bf2f(u1[0]), a1 = bf2f(u1[1]);
        const float c0 = bf2f(u2[0]), c1 = bf2f(u2[1]);
        s1a += a0; s1b += a1;
        s2a += c0; s2b += c1;
        ushort o[2];
        o[0] = f2bf(a0 + c0);
        o[1] = f2bf(a1 + c1);
        *reinterpret_cast<unsigned*>(Sb + idx) = *reinterpret_cast<unsigned*>(o);
    }
    float* gp = Gp + (size_t)blockIdx.x * 1024;
    gp[d0] = s1a; gp[d0 + 1] = s1b;
    gp[512 + d0] = s2a; gp[512 + d0 + 1] = s2b;
}

// ---------------------------------------------------------------------------
// gate GEMV: y[b][512] = mean-vec(xs) @ ag_w1 + b1. grid (8 jc, 8 b).
// ---------------------------------------------------------------------------
__global__ __launch_bounds__(256) void gate1_k(const float* __restrict__ Gp,
                                               const float* __restrict__ w1,
                                               const float* __restrict__ b1,
                                               float* __restrict__ y)
{
    __shared__ float xs[1024];
    __shared__ float red[4][64];
    const int jc = blockIdx.x, b = blockIdx.y, tid = threadIdx.x;
    for (int k = tid; k < 1024; k += 256) {
        float s = 0.f;
        #pragma unroll 8
        for (int c = 0; c < 32; ++c) s += Gp[(size_t)(b * 32 + c) * 1024 + k];
        xs[k] = s * (1.0f / N_);
    }
    __syncthreads();
    const int jl = tid & 63;
    const int jj = jc * 64 + jl;
    const int seg = tid >> 6;
    float acc = 0.f;
    const float* wp = w1 + (size_t)(seg * 256) * 512 + jj;
    const float* xp = xs + seg * 256;
    #pragma unroll 8
    for (int k = 0; k < 256; ++k) acc += xp[k] * wp[(size_t)k * 512];
    red[seg][jl] = acc;
    __syncthreads();
    if (tid < 64)
        y[b * 512 + jc * 64 + tid] =
            red[0][tid] + red[1][tid] + red[2][tid] + red[3][tid] + b1[jc * 64 + tid];
}

// ---------------------------------------------------------------------------
// gate tail: LN(512) -> GELU -> @ag_w2[512,3]+b2 -> softmax. grid = 8 blocks.
// ---------------------------------------------------------------------------
__global__ __launch_bounds__(256) void gate2_k(const float* __restrict__ y,
                                               const float* __restrict__ lng,
                                               const float* __restrict__ lnb,
                                               const float* __restrict__ w2,
                                               const float* __restrict__ b2,
                                               float* __restrict__ gate)
{
    __shared__ float red[4];
    const int b = blockIdx.x, tid = threadIdx.x;
    const float v0 = y[b * 512 + tid];
    const float v1 = y[b * 512 + 256 + tid];
    const float s = blk_sum(v0 + v1, red);
    const float ss = blk_sum(v0 * v0 + v1 * v1, red);
    const float mu = s * (1.0f / 512.0f);
    const float var = ss * (1.0f / 512.0f) - mu * mu;
    const float rs = rsqrtf(var + 1e-5f);
    const float z0 = gelu_f((v0 - mu) * rs * lng[tid] + lnb[tid]);
    const float z1 = gelu_f((v1 - mu) * rs * lng[tid + 256] + lnb[tid + 256]);
    float p0 = z0 * w2[tid * 3 + 0] + z1 * w2[(tid + 256) * 3 + 0];
    float p1 = z0 * w2[tid * 3 + 1] + z1 * w2[(tid + 256) * 3 + 1];
    float p2 = z0 * w2[tid * 3 + 2] + z1 * w2[(tid + 256) * 3 + 2];
    p0 = blk_sum(p0, red);
    p1 = blk_sum(p1, red);
    p2 = blk_sum(p2, red);
    if (tid == 0) {
        p0 += b2[0]; p1 += b2[1]; p2 += b2[2];
        const float m = fmaxf(p0, fmaxf(p1, p2));
        const float e0 = expf(p0 - m), e1 = expf(p1 - m), e2 = expf(p2 - m);
        const float inv = 1.0f / (e0 + e1 + e2);
        gate[b * 3 + 0] = e0 * inv;
        gate[b * 3 + 1] = e1 * inv;
        gate[b * 3 + 2] = e2 * inv;
    }
}

// ---------------------------------------------------------------------------
// fused = g0*spec + g1*spat + g2*vol (all bf16); writes bf16
// ---------------------------------------------------------------------------
__global__ __launch_bounds__(256) void fuse_k(
    const ushort* __restrict__ spec, const ushort* __restrict__ spat,
    const ushort* __restrict__ volb, const float* __restrict__ gate,
    ushort* __restrict__ fb)
{
    const size_t i4 = ((size_t)blockIdx.x * 256 + threadIdx.x) * 4;
    const int b = (int)(i4 >> 19);
    const float g0 = gate[b * 3 + 0], g1 = gate[b * 3 + 1], g2 = gate[b * 3 + 2];
    ushort au[4], cu[4], vu[4];
    *reinterpret_cast<uint2*>(au) = *reinterpret_cast<const uint2*>(spec + i4);
    *reinterpret_cast<uint2*>(cu) = *reinterpret_cast<const uint2*>(spat + i4);
    *reinterpret_cast<uint2*>(vu) = *reinterpret_cast<const uint2*>(volb + i4);
    union { ushort s[4]; uint2 u; } ob;
    #pragma unroll
    for (int e = 0; e < 4; ++e)
        ob.s[e] = f2bf(g0 * bf2f(au[e]) + g1 * bf2f(cu[e]) + g2 * bf2f(vu[e]));
    *reinterpret_cast<uint2*>(fb + i4) = ob.u;
}

// ---------------------------------------------------------------------------
extern "C" void kernel_launch(void* const* d_in, const int* in_sizes, int n_in,
                              void* d_out, int out_size, void* d_ws, size_t ws_size,
                              hipStream_t stream)
{
    const float* hsi    = (const float*)d_in[0];
    const float* lidar  = (const float*)d_in[1];
    const float* temp   = (const float*)d_in[2];
    const float* sq_w   = (const float*)d_in[3];
    const float* sq_b   = (const float*)d_in[4];
    const float* sq_lng = (const float*)d_in[5];
    const float* sq_lnb = (const float*)d_in[6];
    const float* sproj_w = (const float*)d_in[7];
    const float* sproj_b = (const float*)d_in[8];
    const float* pq_w   = (const float*)d_in[9];
    const float* pq_b   = (const float*)d_in[10];
    const float* pq_lng = (const float*)d_in[11];
    const float* pq_lnb = (const float*)d_in[12];
    const float* pproj_w = (const float*)d_in[13];
    const float* pproj_b = (const float*)d_in[14];
    const float* vf_w1  = (const float*)d_in[15];
    const float* vf_b1  = (const float*)d_in[16];
    const float* vf_w2  = (const float*)d_in[17];
    const float* vf_b2  = (const float*)d_in[18];
    const float* ag_w1  = (const float*)d_in[19];
    const float* ag_b1  = (const float*)d_in[20];
    const float* ag_lng = (const float*)d_in[21];
    const float* ag_lnb = (const float*)d_in[22];
    const float* ag_w2  = (const float*)d_in[23];
    const float* ag_b2  = (const float*)d_in[24];
    const float* fr_w1  = (const float*)d_in[25];
    const float* fr_b1  = (const float*)d_in[26];
    const float* fr_w2  = (const float*)d_in[27];
    const float* fr_b2  = (const float*)d_in[28];
    const float* alpha  = (const float*)d_in[29];
    const float* beta   = (const float*)d_in[30];
    float* out = (float*)d_out;

    // ---- workspace layout (ushort units; peak ~117.4 MB) ----
    ushort* base = (ushort*)d_ws;
    ushort* Qkv  = base;                 // [16384][1536] bf16 (50.3 MB), qkv+Q
    ushort* Ob   = base;                 //   after attn: [16384][512] proj out
    ushort* Sb   = base + 8388608;       //   [8192][512] spec+spat bf16
    ushort* volb = base + 12582912;      //   [8192][512] volumetric bf16
    ushort* fb   = base + 16777216;      //   [8192][512] fused bf16
    float*  Gp   = (float*)(base + 20971520);  // [256][1024] f32 partials
    float*  gate = Gp + 262144;
    float*  ybuf = gate + 64;            //   [8][512]
    ushort* Kb   = base + 25165824;      // [128][1024][64] bf16 (16.8 MB)
    ushort* Vt   = base + 33554432;      // [128][64][1024] bf16 (16.8 MB)
    ushort* Hb   = base + 25165824;      //   after attn: [8192][1024] MLP hidden
    ushort* Ab   = base + 41943040;      // [16384][512] attn out bf16 (16.8 MB)
    ushort* Xb   = base + 41943040;      //   (pre-attn) [16384][512] bf16 inputs
    ushort* Wb   = base + 50331648;      // bf16 weights pool (8.4 MB)
    ushort* Rb   = base + 54525952;      // [8192][512] bf16 0.5*(hsi+lidar)

    const dim3 blk(256);

    // ---- weight + input conversion (Rb = 0.5*(hsi+lidar) for final residual)
    cvtw_k<<<dim3(24, 16, 8), blk, 0, stream>>>(sq_w, pq_w, sproj_w, pproj_w,
                                                vf_w1, vf_w2, fr_w1, fr_w2, Wb);
    cvt3_k<<<2048, blk, 0, stream>>>(hsi, lidar, Xb, Xb + (size_t)M_ * D_, Rb);

    // ---- qkv for BOTH branches (grouped, 128x128 tile — proven best)
    pgemm_k<128,128,0,1,false,true><<<1536, blk, 0, stream>>>(
        Xb, Wb + WOFF_SQ, Wb + WOFF_PQ, sq_b, pq_b, M_,
        Qkv, 12, D3_, D_, nullptr, nullptr, nullptr, nullptr);

    // ---- LN + l2norm + K/V prep, both branches (vectorized)
    lnprep_k<<<2048, blk, 0, stream>>>(Qkv, sq_lng, sq_lnb, pq_lng, pq_lnb,
                                       temp, Kb, Vt);

    // ---- attention, both branches
    fattn_k<<<1024, blk, 0, stream>>>(Qkv, Kb, Vt, temp, Ab);

    // ---- projection for BOTH branches (grouped) -> Ob bf16
    pgemm_k<128,64,0,1,false,true><<<1024, blk, 0, stream>>>(
        Ab, Wb + WOFF_SPROJ, Wb + WOFF_PPROJ, sproj_b, pproj_b, M_,
        Ob, 8, D_, D_, nullptr, nullptr, nullptr, nullptr);

    const ushort* spec_b = Ob;
    const ushort* spat_b = Ob + (size_t)M_ * D_;

    // ---- one pass: Sb = spec+spat AND gate column partials; gate MLP (2-stage)
    sums_k<<<256, blk, 0, stream>>>(spec_b, spat_b, Sb, Gp);
    gate1_k<<<dim3(8, 8), blk, 0, stream>>>(Gp, ag_w1, ag_b1, ybuf);
    gate2_k<<<B_, blk, 0, stream>>>(ybuf, ag_lng, ag_lnb, ag_w2, ag_b2, gate);

    // ---- volumetric MLP: Hb = gelu(Sb@vf_w1); volb = Hb@vf_w2
    pgemm_k<128,64,1,1,false,false><<<1024, blk, 0, stream>>>(
        Sb, Wb + WOFF_VF1, nullptr, vf_b1, nullptr, 0,
        Hb, 16, 1024, D_, nullptr, nullptr, nullptr, nullptr);
    pgemm_k<128,64,0,1,false,false><<<512, blk, 0, stream>>>(
        Hb, Wb + WOFF_VF2, nullptr, vf_b2, nullptr, 0,
        volb, 8, D_, 1024, nullptr, nullptr, nullptr, nullptr);

    // ---- fuse + recal MLP + final combine
    fuse_k<<<4096, blk, 0, stream>>>(spec_b, spat_b, volb, gate, fb);
    pgemm_k<128,64,1,1,false,false><<<1024, blk, 0, stream>>>(
        fb, Wb + WOFF_FR1, nullptr, fr_b1, nullptr, 0,
        Hb, 16, 1024, D_, nullptr, nullptr, nullptr, nullptr);
    pgemm_k<128,64,0,0,true,false><<<512, blk, 0, stream>>>(
        Hb, Wb + WOFF_FR2, nullptr, fr_b2, nullptr, 0,
        out, 8, D_, 1024, fb, Rb, alpha, beta);
}

// Round 17
// 322.605 us; speedup vs baseline: 1.2738x; 1.0152x over previous
//
#include <hip/hip_runtime.h>
#include <hip/hip_bf16.h>
#include <math.h>

#define B_   8
#define N_   1024
#define D_   512
#define H_   8
#define HD_  64
#define D3_  1536
#define M_   (B_ * N_)   // 8192 tokens per branch; 16384 combined

// bf16 weight-pool offsets (elements)
#define WOFF_SQ    0
#define WOFF_PQ    786432
#define WOFF_SPROJ 1572864
#define WOFF_PPROJ 1835008
#define WOFF_VF1   2097152
#define WOFF_VF2   2621440
#define WOFF_FR1   3145728
#define WOFF_FR2   3670016

typedef float f32x4 __attribute__((ext_vector_type(4)));
typedef __bf16 bf16x8 __attribute__((ext_vector_type(8)));

union FragU {
    uint4 u4;
    unsigned int u[4];
    ushort s[8];
    bf16x8 v;
};

static __device__ __forceinline__ ushort f2bf(float x) {
    union { __bf16 h; ushort u; } c;
    c.h = (__bf16)x;
    return c.u;
}

static __device__ __forceinline__ float bf2f(ushort u) {
    union { unsigned u; float f; } c;
    c.u = ((unsigned)u) << 16;
    return c.f;
}

static __device__ __forceinline__ unsigned int pack2(float a, float b) {
    return (unsigned int)f2bf(a) | ((unsigned int)f2bf(b) << 16);
}

static __device__ __forceinline__ float gelu_f(float x) {
    return 0.5f * x * (1.0f + erff(x * 0.7071067811865475f));
}

#if __has_builtin(__builtin_amdgcn_exp2f)
static __device__ __forceinline__ float exp2_fast(float x) { return __builtin_amdgcn_exp2f(x); }
#else
static __device__ __forceinline__ float exp2_fast(float x) { return exp2f(x); }
#endif

// async global->LDS, 16B per lane; lds base must be wave-uniform
static __device__ __forceinline__ void gload16(const ushort* g, ushort* lds) {
    __builtin_amdgcn_global_load_lds(
        (const __attribute__((address_space(1))) void*)g,
        (__attribute__((address_space(3))) void*)lds, 16, 0, 0);
}

// block-wide sum, blockDim.x == 256 (4 waves)
static __device__ __forceinline__ float blk_sum(float v, float* red) {
    #pragma unroll
    for (int off = 32; off; off >>= 1) v += __shfl_xor(v, off);
    const int w = threadIdx.x >> 6;
    __syncthreads();
    if ((threadIdx.x & 63) == 0) red[w] = v;
    __syncthreads();
    return red[0] + red[1] + red[2] + red[3];
}

// ---------------------------------------------------------------------------
// bf16 MFMA GEMM (BK=32, fragment-major LDS, global_load_lds, 2-phase
// prefetch). Templated BMxBN tile, 4 waves.
// GROUP: rows >= Msplit use Wt2/bias2 (two-branch batched GEMM).
// OUT: 0 = f32; 1 = bf16; 3 = gate-fused bf16:
//      C = bf16(g0*bf2f(fusedb) + g1*bf2f(resb) + g2*(acc+bias)),
//      g = alphap[3*(m>>10) .. +2]  (per-batch gate weights).
// ACT: 1 = exact GELU.
// FINAL: C = bf2f(fusedb) + alpha*(acc+bias) + beta*bf2f(resb)   (f32 out)
// XCD-chunked swizzle (grid % 8 == 0), m-major block order.
// ---------------------------------------------------------------------------
template <int BM, int BN, int ACT, int OUT, bool FINAL, bool GROUP>
__global__ __launch_bounds__(256) void pgemm_k(
    const ushort* __restrict__ A, const ushort* __restrict__ Wt,
    const ushort* __restrict__ Wt2, const float* __restrict__ bias,
    const float* __restrict__ bias2, int Msplit,
    void* __restrict__ Cv, int nbx, int Nn, int K,
    const ushort* __restrict__ fusedb, const ushort* __restrict__ resb,
    const float* __restrict__ alphap, const float* __restrict__ betap)
{
    constexpr int MI = BM / 32;     // A frags per wave
    constexpr int NJ = BN / 32;     // B frags per wave
    constexpr int CA = BM / 16;     // A staging chunks
    constexpr int CB = BN / 16;
    __shared__ ushort Asm[2][BM * 32];
    __shared__ ushort Bsm[2][BN * 32];
    const int tid = threadIdx.x;
    const int w = tid >> 6, l = tid & 63;
    const int cpx = gridDim.x >> 3;
    const int wg = (blockIdx.x & 7) * cpx + (blockIdx.x >> 3);
    const int m0 = (wg / nbx) * BM, n0 = (wg % nbx) * BN;
    const int wr = w >> 1, wc = w & 1;
    const int lr = l & 15, g = l >> 4;

    const ushort* W_ = (!GROUP || m0 < Msplit) ? Wt : Wt2;
    const float* b_ = (!GROUP || m0 < Msplit) ? bias : bias2;

    f32x4 acc[MI][NJ] = {};
    const int nt = K >> 5;

    #define STAGE(buf, kt)                                                        \
        do {                                                                      \
            const int k0s = (kt) << 5;                                            \
            for (int c = w; c < CA; c += 4)                                       \
                gload16(&A[(size_t)(m0 + c * 16 + lr) * K + k0s + 8 * g],         \
                        &Asm[buf][c * 512]);                                      \
            for (int c = w; c < CB; c += 4)                                       \
                gload16(&W_[(size_t)(n0 + c * 16 + lr) * K + k0s + 8 * g],        \
                        &Bsm[buf][c * 512]);                                      \
        } while (0)

    STAGE(0, 0);
    __syncthreads();
    int cur = 0;
    for (int t = 0; t < nt; ++t) {
        if (t + 1 < nt) STAGE(cur ^ 1, t + 1);
        FragU af[MI], bf4[NJ];
        #pragma unroll
        for (int mi = 0; mi < MI; ++mi)
            af[mi].u4 = *reinterpret_cast<const uint4*>(
                &Asm[cur][(wr * MI + mi) * 512 + l * 8]);
        #pragma unroll
        for (int nj = 0; nj < NJ; ++nj)
            bf4[nj].u4 = *reinterpret_cast<const uint4*>(
                &Bsm[cur][(wc * NJ + nj) * 512 + l * 8]);
        #pragma unroll
        for (int mi = 0; mi < MI; ++mi)
            #pragma unroll
            for (int nj = 0; nj < NJ; ++nj)
                acc[mi][nj] = __builtin_amdgcn_mfma_f32_16x16x32_bf16(
                    af[mi].v, bf4[nj].v, acc[mi][nj], 0, 0, 0);
        __syncthreads();
        cur ^= 1;
    }
    #undef STAGE

    float alpha = 0.f, beta = 0.f;
    if (FINAL) { alpha = alphap[0]; beta = betap[0]; }
    #pragma unroll
    for (int mi = 0; mi < MI; ++mi) {
        #pragma unroll
        for (int r = 0; r < 4; ++r) {
            const int m = m0 + wr * (MI * 16) + mi * 16 + g * 4 + r;
            float g0 = 0.f, g1 = 0.f, g2 = 0.f;
            if (OUT == 3) {
                const int bidx = m >> 10;
                g0 = alphap[3 * bidx];
                g1 = alphap[3 * bidx + 1];
                g2 = alphap[3 * bidx + 2];
            }
            #pragma unroll
            for (int nj = 0; nj < NJ; ++nj) {
                const int n = n0 + wc * (NJ * 16) + nj * 16 + lr;
                const size_t idx = (size_t)m * Nn + n;
                float v = acc[mi][nj][r] + b_[n];
                if (ACT == 1) v = gelu_f(v);
                if (FINAL)
                    v = bf2f(fusedb[idx]) + alpha * v + beta * bf2f(resb[idx]);
                if (OUT == 0) ((float*)Cv)[idx] = v;
                else if (OUT == 1) ((ushort*)Cv)[idx] = f2bf(v);
                else {  // OUT == 3: gate-fused epilogue
                    ((ushort*)Cv)[idx] = f2bf(
                        g0 * bf2f(fusedb[idx]) + g1 * bf2f(resb[idx]) + g2 * v);
                }
            }
        }
    }
}

// ---------------------------------------------------------------------------
// weight convert+transpose: Wt[n][k] = bf16(W[k][n]); 8 weights via blockIdx.z
// ---------------------------------------------------------------------------
__global__ __launch_bounds__(256) void cvtw_k(
    const float* __restrict__ w0, const float* __restrict__ w1,
    const float* __restrict__ w2, const float* __restrict__ w3,
    const float* __restrict__ w4, const float* __restrict__ w5,
    const float* __restrict__ w6, const float* __restrict__ w7,
    ushort* __restrict__ dst)
{
    __shared__ ushort T[64][72];
    const int id = blockIdx.z;
    int K, Nn, off;
    const float* src;
    switch (id) {
        case 0: src = w0; K = 512;  Nn = 1536; off = WOFF_SQ;    break;
        case 1: src = w1; K = 512;  Nn = 1536; off = WOFF_PQ;    break;
        case 2: src = w2; K = 512;  Nn = 512;  off = WOFF_SPROJ; break;
        case 3: src = w3; K = 512;  Nn = 512;  off = WOFF_PPROJ; break;
        case 4: src = w4; K = 512;  Nn = 1024; off = WOFF_VF1;   break;
        case 5: src = w5; K = 1024; Nn = 512;  off = WOFF_VF2;   break;
        case 6: src = w6; K = 512;  Nn = 1024; off = WOFF_FR1;   break;
        default: src = w7; K = 1024; Nn = 512; off = WOFF_FR2;   break;
    }
    const int n0 = blockIdx.x * 64, k0 = blockIdx.y * 64;
    if (n0 >= Nn || k0 >= K) return;
    const int t = threadIdx.x;
    const int q = t >> 6, e = t & 63;
    #pragma unroll 4
    for (int i = 0; i < 16; ++i) {
        const int kl = q * 16 + i;
        T[e][kl] = f2bf(src[(size_t)(k0 + kl) * Nn + n0 + e]);
    }
    __syncthreads();
    #pragma unroll 4
    for (int i = 0; i < 16; ++i) {
        const int nl = q * 16 + i;
        dst[(size_t)off + (size_t)(n0 + nl) * K + k0 + e] = T[nl][e];
    }
}

// ---------------------------------------------------------------------------
// input convert: xh = bf16(h), xl = bf16(l), rb = bf16(0.5*(h+l)); 8/thread
// ---------------------------------------------------------------------------
__global__ __launch_bounds__(256) void cvt3_k(const float* __restrict__ h,
                                              const float* __restrict__ l,
                                              ushort* __restrict__ xh,
                                              ushort* __restrict__ xl,
                                              ushort* __restrict__ rb)
{
    const size_t i = ((size_t)blockIdx.x * 256 + threadIdx.x) * 8;
    const float4 h0 = *reinterpret_cast<const float4*>(h + i);
    const float4 h1 = *reinterpret_cast<const float4*>(h + i + 4);
    const float4 l0 = *reinterpret_cast<const float4*>(l + i);
    const float4 l1 = *reinterpret_cast<const float4*>(l + i + 4);
    FragU oh, ol, orr;
    oh.u[0] = pack2(h0.x, h0.y); oh.u[1] = pack2(h0.z, h0.w);
    oh.u[2] = pack2(h1.x, h1.y); oh.u[3] = pack2(h1.z, h1.w);
    ol.u[0] = pack2(l0.x, l0.y); ol.u[1] = pack2(l0.z, l0.w);
    ol.u[2] = pack2(l1.x, l1.y); ol.u[3] = pack2(l1.z, l1.w);
    orr.u[0] = pack2(0.5f * (h0.x + l0.x), 0.5f * (h0.y + l0.y));
    orr.u[1] = pack2(0.5f * (h0.z + l0.z), 0.5f * (h0.w + l0.w));
    orr.u[2] = pack2(0.5f * (h1.x + l1.x), 0.5f * (h1.y + l1.y));
    orr.u[3] = pack2(0.5f * (h1.z + l1.z), 0.5f * (h1.w + l1.w));
    *reinterpret_cast<uint4*>(xh + i) = oh.u4;
    *reinterpret_cast<uint4*>(xl + i) = ol.u4;
    *reinterpret_cast<uint4*>(rb + i) = orr.u4;
}

// ---------------------------------------------------------------------------
// Fused LN(1536) + head split + l2norm, bf16 in/out, both branches.
// VECTORIZED: lane l holds 8 contiguous elems per 512-chunk (q/k/v);
// per-head l2norm = 3-shuffle reduce over the aligned 8-lane group.
// ---------------------------------------------------------------------------
__global__ __launch_bounds__(256) void lnprep_k(ushort* __restrict__ x,
                                                const float* __restrict__ lng0,
                                                const float* __restrict__ lnb0,
                                                const float* __restrict__ lng1,
                                                const float* __restrict__ lnb1,
                                                const float* __restrict__ temp,
                                                ushort* __restrict__ Kb,
                                                ushort* __restrict__ Vt)
{
    __shared__ ushort Vs[8 * 512];
    const int w = threadIdx.x >> 6, l = threadIdx.x & 63;
    const int n0 = blockIdx.x * 8;
    const float L2E = 1.4426950408889634f;
    const float* lng = (n0 < 8192) ? lng0 : lng1;
    const float* lnb = (n0 < 8192) ? lnb0 : lnb1;
    const int hd8 = l >> 3;          // head for q/k chunks
    const int d8  = (l & 7) * 8;     // dim base within head
    const float tL = temp[hd8] * L2E;

    float gq[8], bq[8], gk[8], bk[8], gv[8], bv[8];
    #pragma unroll
    for (int e = 0; e < 8; ++e) {
        gq[e] = lng[8 * l + e];          bq[e] = lnb[8 * l + e];
        gk[e] = lng[512 + 8 * l + e];    bk[e] = lnb[512 + 8 * l + e];
        gv[e] = lng[1024 + 8 * l + e];   bv[e] = lnb[1024 + 8 * l + e];
    }

    #pragma unroll
    for (int rr = 0; rr < 2; ++rr) {
        const int row = n0 + w * 2 + rr;
        const int bb = row >> 10;        // 0..15
        const int n = row & 1023;
        ushort* xr = x + (size_t)row * D3_;
        FragU cq, ck, cv;
        cq.u4 = *reinterpret_cast<const uint4*>(xr + 8 * l);
        ck.u4 = *reinterpret_cast<const uint4*>(xr + 512 + 8 * l);
        cv.u4 = *reinterpret_cast<const uint4*>(xr + 1024 + 8 * l);
        float q[8], k[8], v[8];
        float s = 0.f, ss = 0.f;
        #pragma unroll
        for (int e = 0; e < 8; ++e) {
            q[e] = bf2f(cq.s[e]); k[e] = bf2f(ck.s[e]); v[e] = bf2f(cv.s[e]);
            s += q[e] + k[e] + v[e];
            ss += q[e] * q[e] + k[e] * k[e] + v[e] * v[e];
        }
        #pragma unroll
        for (int off = 32; off; off >>= 1) {
            s += __shfl_xor(s, off);
            ss += __shfl_xor(ss, off);
        }
        const float mu = s * (1.0f / D3_);
        const float var = ss * (1.0f / D3_) - mu * mu;
        const float rs = rsqrtf(var + 1e-5f);
        float sq = 0.f, sk = 0.f;
        #pragma unroll
        for (int e = 0; e < 8; ++e) {
            q[e] = (q[e] - mu) * rs * gq[e] + bq[e];
            k[e] = (k[e] - mu) * rs * gk[e] + bk[e];
            v[e] = (v[e] - mu) * rs * gv[e] + bv[e];
            sq += q[e] * q[e];
            sk += k[e] * k[e];
        }
        #pragma unroll
        for (int off = 4; off; off >>= 1) {
            sq += __shfl_xor(sq, off);
            sk += __shfl_xor(sk, off);
        }
        const float qs = tL / fmaxf(sqrtf(sq), 1e-12f);
        const float ks = 1.0f / fmaxf(sqrtf(sk), 1e-12f);
        FragU oq, ok, ov;
        #pragma unroll
        for (int e = 0; e < 8; ++e) {
            oq.s[e] = f2bf(q[e] * qs);
            ok.s[e] = f2bf(k[e] * ks);
            ov.s[e] = f2bf(v[e]);
        }
        *reinterpret_cast<uint4*>(xr + 8 * l) = oq.u4;   // Q in place
        *reinterpret_cast<uint4*>(
            &Kb[((size_t)(bb * 8 + hd8) * N_ + n) * HD_ + d8]) = ok.u4;
        *reinterpret_cast<uint4*>(&Vs[(w * 2 + rr) * 512 + 8 * l]) = ov.u4;
    }
    __syncthreads();
    const int bb = n0 >> 10;
    #pragma unroll
    for (int it = 0; it < 2; ++it) {
        const int combo = threadIdx.x + it * 256;   // h*64 + d
        FragU f;
        #pragma unroll
        for (int tok = 0; tok < 8; ++tok) f.s[tok] = Vs[tok * 512 + combo];
        *reinterpret_cast<uint4*>(
            &Vt[((size_t)(bb * 8 + (combo >> 6)) * HD_ + (combo & 63)) * N_ + (n0 & 1023)]) = f.u4;
    }
}

// ---------------------------------------------------------------------------
// Flash-style cosine attention, both branches. grid 1024, XCD-swizzled.
// Round-11 structure (best measured): double-buffered Ks/Vs LDS (one barrier
// per KV tile), setprio around MFMA cluster, softmax shift folded into MFMA
// C-init, lsum via ones-MFMA.
// ---------------------------------------------------------------------------
__global__ __launch_bounds__(256) void fattn_k(const ushort* __restrict__ Qu,
                                               const ushort* __restrict__ Kb,
                                               const ushort* __restrict__ Vt,
                                               const float* __restrict__ temp,
                                               ushort* __restrict__ out)
{
    __shared__ ushort Ks[2][64 * 72];
    __shared__ ushort Vs[2][64 * 72];
    const int tid = threadIdx.x;
    const int cpx = gridDim.x >> 3;
    const int wg = (blockIdx.x & 7) * cpx + (blockIdx.x >> 3);
    const int nb = wg & 7;
    const int h  = (wg >> 3) & 7;
    const int bb = wg >> 6;          // 0..15
    const int bh = bb * 8 + h;       // 0..127
    const int n0 = nb * 128;
    const int w  = tid >> 6;
    const int l  = tid & 63;
    const int lr = l & 15;
    const int g  = l >> 4;
    const float m2 = fabsf(temp[h]) * 1.4426950408889634f;
    const f32x4 mInit = {-m2, -m2, -m2, -m2};

    FragU ones;
    ones.u[0] = ones.u[1] = ones.u[2] = ones.u[3] = 0x3F803F80u;

    const int qb = n0 + w * 32;
    FragU qa0, qa1, qb0, qb1;
    {
        const size_t rb0 = (size_t)(bb * N_ + qb + lr) * D3_ + h * 64 + 8 * g;
        const size_t rb1 = (size_t)(bb * N_ + qb + 16 + lr) * D3_ + h * 64 + 8 * g;
        qa0.u4 = *reinterpret_cast<const uint4*>(&Qu[rb0]);
        qa1.u4 = *reinterpret_cast<const uint4*>(&Qu[rb0 + 32]);
        qb0.u4 = *reinterpret_cast<const uint4*>(&Qu[rb1]);
        qb1.u4 = *reinterpret_cast<const uint4*>(&Qu[rb1 + 32]);
    }

    f32x4 OA[4] = {};
    f32x4 OB[4] = {};
    f32x4 LSA = {0.f, 0.f, 0.f, 0.f};
    f32x4 LSB = {0.f, 0.f, 0.f, 0.f};

    const ushort* kbase = Kb + (size_t)bh * N_ * HD_;
    const ushort* vbase = Vt + (size_t)bh * HD_ * N_;
    const int sr = tid >> 3;
    const int sc = (tid & 7) * 8;
    uint4 k0r, k1r, v0r, v1r;

    #define LOADT(kt)                                                           \
        do {                                                                    \
            const ushort* ks_ = kbase + (size_t)((kt) * 64) * HD_;              \
            const ushort* vs_ = vbase + (kt) * 64;                              \
            k0r = *reinterpret_cast<const uint4*>(ks_ + sr * HD_ + sc);         \
            k1r = *reinterpret_cast<const uint4*>(ks_ + (sr + 32) * HD_ + sc);  \
            v0r = *reinterpret_cast<const uint4*>(vs_ + (size_t)sr * N_ + sc);  \
            v1r = *reinterpret_cast<const uint4*>(vs_ + (size_t)(sr + 32) * N_ + sc); \
        } while (0)
    #define WRITET(p)                                                           \
        do {                                                                    \
            *reinterpret_cast<uint4*>(&Ks[p][sr * 72 + sc]) = k0r;              \
            *reinterpret_cast<uint4*>(&Ks[p][(sr + 32) * 72 + sc]) = k1r;       \
            *reinterpret_cast<uint4*>(&Vs[p][sr * 72 + sc]) = v0r;              \
            *reinterpret_cast<uint4*>(&Vs[p][(sr + 32) * 72 + sc]) = v1r;       \
        } while (0)

    LOADT(0);
    WRITET(0);

    #pragma unroll 1
    for (int kt = 0; kt < 16; ++kt) {
        const int p = kt & 1;
        __syncthreads();               // buf p fully written; buf p^1 free
        if (kt < 15) LOADT(kt + 1);    // global->reg, overlaps compute

        unsigned paA[2][4], paB[2][4];
        #pragma unroll
        for (int j = 0; j < 4; ++j) {
            FragU ka, kc;
            ka.u4 = *reinterpret_cast<const uint4*>(&Ks[p][(j * 16 + lr) * 72 + 8 * g]);
            kc.u4 = *reinterpret_cast<const uint4*>(&Ks[p][(j * 16 + lr) * 72 + 32 + 8 * g]);
            f32x4 sA = mInit, sB = mInit;
            sA = __builtin_amdgcn_mfma_f32_16x16x32_bf16(ka.v, qa0.v, sA, 0, 0, 0);
            sA = __builtin_amdgcn_mfma_f32_16x16x32_bf16(kc.v, qa1.v, sA, 0, 0, 0);
            sB = __builtin_amdgcn_mfma_f32_16x16x32_bf16(ka.v, qb0.v, sB, 0, 0, 0);
            sB = __builtin_amdgcn_mfma_f32_16x16x32_bf16(kc.v, qb1.v, sB, 0, 0, 0);
            float pA[4], pB[4];
            #pragma unroll
            for (int r = 0; r < 4; ++r) {
                pA[r] = exp2_fast(sA[r]);
                pB[r] = exp2_fast(sB[r]);
            }
            paA[j >> 1][2 * (j & 1) + 0] = pack2(pA[0], pA[1]);
            paA[j >> 1][2 * (j & 1) + 1] = pack2(pA[2], pA[3]);
            paB[j >> 1][2 * (j & 1) + 0] = pack2(pB[0], pB[1]);
            paB[j >> 1][2 * (j & 1) + 1] = pack2(pB[2], pB[3]);
        }

        __builtin_amdgcn_s_setprio(1);
        #pragma unroll
        for (int ks = 0; ks < 2; ++ks) {
            FragU fa, fb2;
            fa.u[0] = paA[ks][0]; fa.u[1] = paA[ks][1];
            fa.u[2] = paA[ks][2]; fa.u[3] = paA[ks][3];
            fb2.u[0] = paB[ks][0]; fb2.u[1] = paB[ks][1];
            fb2.u[2] = paB[ks][2]; fb2.u[3] = paB[ks][3];
            LSA = __builtin_amdgcn_mfma_f32_16x16x32_bf16(fa.v, ones.v, LSA, 0, 0, 0);
            LSB = __builtin_amdgcn_mfma_f32_16x16x32_bf16(fb2.v, ones.v, LSB, 0, 0, 0);
            #pragma unroll
            for (int s4 = 0; s4 < 4; ++s4) {
                FragU vb;
                const int vi = (lr + 16 * s4) * 72 + ks * 32 + 4 * g;
                *reinterpret_cast<uint2*>(&vb.u[0]) =
                    *reinterpret_cast<const uint2*>(&Vs[p][vi]);
                *reinterpret_cast<uint2*>(&vb.u[2]) =
                    *reinterpret_cast<const uint2*>(&Vs[p][vi + 16]);
                OA[s4] = __builtin_amdgcn_mfma_f32_16x16x32_bf16(fa.v, vb.v, OA[s4], 0, 0, 0);
                OB[s4] = __builtin_amdgcn_mfma_f32_16x16x32_bf16(fb2.v, vb.v, OB[s4], 0, 0, 0);
            }
        }
        __builtin_amdgcn_s_setprio(0);

        if (kt < 15) WRITET(p ^ 1);    // other buffer: no wave reads it now
    }
    #undef LOADT
    #undef WRITET

    // LS D-layout: row (= q) is (lane>>4)*4 + r — exactly the rows this lane
    // stores below, so no cross-lane reduction is needed.
    ushort* outp = out + ((size_t)(bb * N_) + qb) * D_ + h * HD_;
    #pragma unroll
    for (int r = 0; r < 4; ++r) {
        const float iA = 1.0f / LSA[r];
        const float iB = 1.0f / LSB[r];
        ushort* rowA = outp + (size_t)(4 * g + r) * D_;
        ushort* rowB = outp + (size_t)(16 + 4 * g + r) * D_;
        #pragma unroll
        for (int s4 = 0; s4 < 4; ++s4) {
            rowA[s4 * 16 + lr] = f2bf(OA[s4][r] * iA);
            rowB[s4 * 16 + lr] = f2bf(OB[s4][r] * iB);
        }
    }
}

// ---------------------------------------------------------------------------
// Merged cvtadd + means: one pass over spec/spat computes
//   Sb = bf16(spec + spat)   AND   Gp column partial sums (32-row chunks).
// grid = B*32 = 256 blocks, 256 thr (2 cols each).
// ---------------------------------------------------------------------------
__global__ __launch_bounds__(256) void sums_k(const ushort* __restrict__ spec,
                                              const ushort* __restrict__ spat,
                                              ushort* __restrict__ Sb,
                                              float* __restrict__ Gp)
{
    const int b = blockIdx.x >> 5;
    const int ch = blockIdx.x & 31;
    const int n0 = ch * 32;
    const int d0 = threadIdx.x * 2;
    float s1a = 0.f, s1b = 0.f, s2a = 0.f, s2b = 0.f;
    #pragma unroll 4
    for (int n = 0; n < 32; ++n) {
        const size_t idx = ((size_t)(b * N_) + n0 + n) * D_ + d0;
        ushort u1[2], u2[2];
        *reinterpret_cast<unsigned*>(u1) = *reinterpret_cast<const unsigned*>(spec + idx);
        *reinterpret_cast<unsigned*>(u2) = *reinterpret_cast<const unsigned*>(spat + idx);
        const float a0 = bf2f(u1[0]), a1 = bf2f(u1[1]);
        const float c0 = bf2f(u2[0]), c1 = bf2f(u2[1]);
        s1a += a0; s1b += a1;
        s2a += c0; s2b += c1;
        ushort o[2];
        o[0] = f2bf(a0 + c0);
        o[1] = f2bf(a1 + c1);
        *reinterpret_cast<unsigned*>(Sb + idx) = *reinterpret_cast<unsigned*>(o);
    }
    float* gp = Gp + (size_t)blockIdx.x * 1024;
    gp[d0] = s1a; gp[d0 + 1] = s1b;
    gp[512 + d0] = s2a; gp[512 + d0 + 1] = s2b;
}

// ---------------------------------------------------------------------------
// gate GEMV: y[b][512] = mean-vec(xs) @ ag_w1 + b1. grid (8 jc, 8 b).
// ---------------------------------------------------------------------------
__global__ __launch_bounds__(256) void gate1_k(const float* __restrict__ Gp,
                                               const float* __restrict__ w1,
                                               const float* __restrict__ b1,
                                               float* __restrict__ y)
{
    __shared__ float xs[1024];
    __shared__ float red[4][64];
    const int jc = blockIdx.x, b = blockIdx.y, tid = threadIdx.x;
    for (int k = tid; k < 1024; k += 256) {
        float s = 0.f;
        #pragma unroll 8
        for (int c = 0; c < 32; ++c) s += Gp[(size_t)(b * 32 + c) * 1024 + k];
        xs[k] = s * (1.0f / N_);
    }
    __syncthreads();
    const int jl = tid & 63;
    const int jj = jc * 64 + jl;
    const int seg = tid >> 6;
    float acc = 0.f;
    const float* wp = w1 + (size_t)(seg * 256) * 512 + jj;
    const float* xp = xs + seg * 256;
    #pragma unroll 8
    for (int k = 0; k < 256; ++k) acc += xp[k] * wp[(size_t)k * 512];
    red[seg][jl] = acc;
    __syncthreads();
    if (tid < 64)
        y[b * 512 + jc * 64 + tid] =
            red[0][tid] + red[1][tid] + red[2][tid] + red[3][tid] + b1[jc * 64 + tid];
}

// ---------------------------------------------------------------------------
// gate tail: LN(512) -> GELU -> @ag_w2[512,3]+b2 -> softmax. grid = 8 blocks.
// ---------------------------------------------------------------------------
__global__ __launch_bounds__(256) void gate2_k(const float* __restrict__ y,
                                               const float* __restrict__ lng,
                                               const float* __restrict__ lnb,
                                               const float* __restrict__ w2,
                                               const float* __restrict__ b2,
                                               float* __restrict__ gate)
{
    __shared__ float red[4];
    const int b = blockIdx.x, tid = threadIdx.x;
    const float v0 = y[b * 512 + tid];
    const float v1 = y[b * 512 + 256 + tid];
    const float s = blk_sum(v0 + v1, red);
    const float ss = blk_sum(v0 * v0 + v1 * v1, red);
    const float mu = s * (1.0f / 512.0f);
    const float var = ss * (1.0f / 512.0f) - mu * mu;
    const float rs = rsqrtf(var + 1e-5f);
    const float z0 = gelu_f((v0 - mu) * rs * lng[tid] + lnb[tid]);
    const float z1 = gelu_f((v1 - mu) * rs * lng[tid + 256] + lnb[tid + 256]);
    float p0 = z0 * w2[tid * 3 + 0] + z1 * w2[(tid + 256) * 3 + 0];
    float p1 = z0 * w2[tid * 3 + 1] + z1 * w2[(tid + 256) * 3 + 1];
    float p2 = z0 * w2[tid * 3 + 2] + z1 * w2[(tid + 256) * 3 + 2];
    p0 = blk_sum(p0, red);
    p1 = blk_sum(p1, red);
    p2 = blk_sum(p2, red);
    if (tid == 0) {
        p0 += b2[0]; p1 += b2[1]; p2 += b2[2];
        const float m = fmaxf(p0, fmaxf(p1, p2));
        const float e0 = expf(p0 - m), e1 = expf(p1 - m), e2 = expf(p2 - m);
        const float inv = 1.0f / (e0 + e1 + e2);
        gate[b * 3 + 0] = e0 * inv;
        gate[b * 3 + 1] = e1 * inv;
        gate[b * 3 + 2] = e2 * inv;
    }
}

// ---------------------------------------------------------------------------
extern "C" void kernel_launch(void* const* d_in, const int* in_sizes, int n_in,
                              void* d_out, int out_size, void* d_ws, size_t ws_size,
                              hipStream_t stream)
{
    const float* hsi    = (const float*)d_in[0];
    const float* lidar  = (const float*)d_in[1];
    const float* temp   = (const float*)d_in[2];
    const float* sq_w   = (const float*)d_in[3];
    const float* sq_b   = (const float*)d_in[4];
    const float* sq_lng = (const float*)d_in[5];
    const float* sq_lnb = (const float*)d_in[6];
    const float* sproj_w = (const float*)d_in[7];
    const float* sproj_b = (const float*)d_in[8];
    const float* pq_w   = (const float*)d_in[9];
    const float* pq_b   = (const float*)d_in[10];
    const float* pq_lng = (const float*)d_in[11];
    const float* pq_lnb = (const float*)d_in[12];
    const float* pproj_w = (const float*)d_in[13];
    const float* pproj_b = (const float*)d_in[14];
    const float* vf_w1  = (const float*)d_in[15];
    const float* vf_b1  = (const float*)d_in[16];
    const float* vf_w2  = (const float*)d_in[17];
    const float* vf_b2  = (const float*)d_in[18];
    const float* ag_w1  = (const float*)d_in[19];
    const float* ag_b1  = (const float*)d_in[20];
    const float* ag_lng = (const float*)d_in[21];
    const float* ag_lnb = (const float*)d_in[22];
    const float* ag_w2  = (const float*)d_in[23];
    const float* ag_b2  = (const float*)d_in[24];
    const float* fr_w1  = (const float*)d_in[25];
    const float* fr_b1  = (const float*)d_in[26];
    const float* fr_w2  = (const float*)d_in[27];
    const float* fr_b2  = (const float*)d_in[28];
    const float* alpha  = (const float*)d_in[29];
    const float* beta   = (const float*)d_in[30];
    float* out = (float*)d_out;

    // ---- workspace layout (ushort units; peak ~117.4 MB) ----
    ushort* base = (ushort*)d_ws;
    ushort* Qkv  = base;                 // [16384][1536] bf16 (50.3 MB), qkv+Q
    ushort* Ob   = base;                 //   after attn: [16384][512] proj out
    ushort* Sb   = base + 8388608;       //   [8192][512] spec+spat bf16
    ushort* fb   = base + 16777216;      //   [8192][512] fused bf16
    float*  Gp   = (float*)(base + 20971520);  // [256][1024] f32 partials
    float*  gate = Gp + 262144;
    float*  ybuf = gate + 64;            //   [8][512]
    ushort* Kb   = base + 25165824;      // [128][1024][64] bf16 (16.8 MB)
    ushort* Vt   = base + 33554432;      // [128][64][1024] bf16 (16.8 MB)
    ushort* Hb   = base + 25165824;      //   after attn: [8192][1024] MLP hidden
    ushort* Ab   = base + 41943040;      // [16384][512] attn out bf16 (16.8 MB)
    ushort* Xb   = base + 41943040;      //   (pre-attn) [16384][512] bf16 inputs
    ushort* Wb   = base + 50331648;      // bf16 weights pool (8.4 MB)
    ushort* Rb   = base + 54525952;      // [8192][512] bf16 0.5*(hsi+lidar)

    const dim3 blk(256);

    // ---- weight + input conversion (Rb = 0.5*(hsi+lidar) for final residual)
    cvtw_k<<<dim3(24, 16, 8), blk, 0, stream>>>(sq_w, pq_w, sproj_w, pproj_w,
                                                vf_w1, vf_w2, fr_w1, fr_w2, Wb);
    cvt3_k<<<2048, blk, 0, stream>>>(hsi, lidar, Xb, Xb + (size_t)M_ * D_, Rb);

    // ---- qkv for BOTH branches (grouped, 128x128 tile — proven best)
    pgemm_k<128,128,0,1,false,true><<<1536, blk, 0, stream>>>(
        Xb, Wb + WOFF_SQ, Wb + WOFF_PQ, sq_b, pq_b, M_,
        Qkv, 12, D3_, D_, nullptr, nullptr, nullptr, nullptr);

    // ---- LN + l2norm + K/V prep, both branches (vectorized)
    lnprep_k<<<2048, blk, 0, stream>>>(Qkv, sq_lng, sq_lnb, pq_lng, pq_lnb,
                                       temp, Kb, Vt);

    // ---- attention, both branches
    fattn_k<<<1024, blk, 0, stream>>>(Qkv, Kb, Vt, temp, Ab);

    // ---- projection for BOTH branches (grouped) -> Ob bf16
    pgemm_k<128,64,0,1,false,true><<<1024, blk, 0, stream>>>(
        Ab, Wb + WOFF_SPROJ, Wb + WOFF_PPROJ, sproj_b, pproj_b, M_,
        Ob, 8, D_, D_, nullptr, nullptr, nullptr, nullptr);

    const ushort* spec_b = Ob;
    const ushort* spat_b = Ob + (size_t)M_ * D_;

    // ---- one pass: Sb = spec+spat AND gate column partials; gate MLP (2-stage)
    sums_k<<<256, blk, 0, stream>>>(spec_b, spat_b, Sb, Gp);
    gate1_k<<<dim3(8, 8), blk, 0, stream>>>(Gp, ag_w1, ag_b1, ybuf);
    gate2_k<<<B_, blk, 0, stream>>>(ybuf, ag_lng, ag_lnb, ag_w2, ag_b2, gate);

    // ---- volumetric MLP: Hb = gelu(Sb@vf_w1); vf2 fuses the gate combine:
    //      fb = bf16(g0*spec + g1*spat + g2*(Hb@vf_w2 + b2))
    pgemm_k<128,64,1,1,false,false><<<1024, blk, 0, stream>>>(
        Sb, Wb + WOFF_VF1, nullptr, vf_b1, nullptr, 0,
        Hb, 16, 1024, D_, nullptr, nullptr, nullptr, nullptr);
    pgemm_k<128,64,0,3,false,false><<<512, blk, 0, stream>>>(
        Hb, Wb + WOFF_VF2, nullptr, vf_b2, nullptr, 0,
        fb, 8, D_, 1024, spec_b, spat_b, gate, nullptr);

    // ---- recal MLP + final combine
    pgemm_k<128,64,1,1,false,false><<<1024, blk, 0, stream>>>(
        fb, Wb + WOFF_FR1, nullptr, fr_b1, nullptr, 0,
        Hb, 16, 1024, D_, nullptr, nullptr, nullptr, nullptr);
    pgemm_k<128,64,0,0,true,false><<<512, blk, 0, stream>>>(
        Hb, Wb + WOFF_FR2, nullptr, fr_b2, nullptr, 0,
        out, 8, D_, 1024, fb, Rb, alpha, beta);
}

// Round 18
// 319.446 us; speedup vs baseline: 1.2864x; 1.0099x over previous
//
#include <hip/hip_runtime.h>
#include <hip/hip_bf16.h>
#include <math.h>

#define B_   8
#define N_   1024
#define D_   512
#define H_   8
#define HD_  64
#define D3_  1536
#define M_   (B_ * N_)   // 8192 tokens per branch; 16384 combined

// bf16 weight-pool offsets (elements)
#define WOFF_SQ    0
#define WOFF_PQ    786432
#define WOFF_SPROJ 1572864
#define WOFF_PPROJ 1835008
#define WOFF_VF1   2097152
#define WOFF_VF2   2621440
#define WOFF_FR1   3145728
#define WOFF_FR2   3670016

typedef float f32x4 __attribute__((ext_vector_type(4)));
typedef __bf16 bf16x8 __attribute__((ext_vector_type(8)));

union FragU {
    uint4 u4;
    unsigned int u[4];
    ushort s[8];
    bf16x8 v;
};

static __device__ __forceinline__ ushort f2bf(float x) {
    union { __bf16 h; ushort u; } c;
    c.h = (__bf16)x;
    return c.u;
}

static __device__ __forceinline__ float bf2f(ushort u) {
    union { unsigned u; float f; } c;
    c.u = ((unsigned)u) << 16;
    return c.f;
}

static __device__ __forceinline__ unsigned int pack2(float a, float b) {
    return (unsigned int)f2bf(a) | ((unsigned int)f2bf(b) << 16);
}

static __device__ __forceinline__ float gelu_f(float x) {
    return 0.5f * x * (1.0f + erff(x * 0.7071067811865475f));
}

#if __has_builtin(__builtin_amdgcn_exp2f)
static __device__ __forceinline__ float exp2_fast(float x) { return __builtin_amdgcn_exp2f(x); }
#else
static __device__ __forceinline__ float exp2_fast(float x) { return exp2f(x); }
#endif

// async global->LDS, 16B per lane; lds base must be wave-uniform
static __device__ __forceinline__ void gload16(const ushort* g, ushort* lds) {
    __builtin_amdgcn_global_load_lds(
        (const __attribute__((address_space(1))) void*)g,
        (__attribute__((address_space(3))) void*)lds, 16, 0, 0);
}

// block-wide sum, blockDim.x == 256 (4 waves)
static __device__ __forceinline__ float blk_sum(float v, float* red) {
    #pragma unroll
    for (int off = 32; off; off >>= 1) v += __shfl_xor(v, off);
    const int w = threadIdx.x >> 6;
    __syncthreads();
    if ((threadIdx.x & 63) == 0) red[w] = v;
    __syncthreads();
    return red[0] + red[1] + red[2] + red[3];
}

// ---------------------------------------------------------------------------
// bf16 MFMA GEMM (BK=32, fragment-major LDS, global_load_lds, 2-phase
// prefetch). Templated BMxBN tile, 4 waves.
// GROUP: rows >= Msplit use Wt2/bias2 (two-branch batched GEMM).
// OUT: 0 = f32; 1 = bf16; 3 = gate-fused bf16:
//      C = bf16(g0*bf2f(fusedb) + g1*bf2f(resb) + g2*(acc+bias)),
//      g = alphap[3*(m>>10) .. +2]  (per-batch gate weights).
// ACT: 1 = exact GELU.
// FINAL: C = bf2f(fusedb) + alpha*(acc+bias) + beta*bf2f(resb)   (f32 out)
// XCD-chunked swizzle (grid % 8 == 0), m-major block order.
// ---------------------------------------------------------------------------
template <int BM, int BN, int ACT, int OUT, bool FINAL, bool GROUP>
__global__ __launch_bounds__(256) void pgemm_k(
    const ushort* __restrict__ A, const ushort* __restrict__ Wt,
    const ushort* __restrict__ Wt2, const float* __restrict__ bias,
    const float* __restrict__ bias2, int Msplit,
    void* __restrict__ Cv, int nbx, int Nn, int K,
    const ushort* __restrict__ fusedb, const ushort* __restrict__ resb,
    const float* __restrict__ alphap, const float* __restrict__ betap)
{
    constexpr int MI = BM / 32;     // A frags per wave
    constexpr int NJ = BN / 32;     // B frags per wave
    constexpr int CA = BM / 16;     // A staging chunks
    constexpr int CB = BN / 16;
    __shared__ ushort Asm[2][BM * 32];
    __shared__ ushort Bsm[2][BN * 32];
    const int tid = threadIdx.x;
    const int w = tid >> 6, l = tid & 63;
    const int cpx = gridDim.x >> 3;
    const int wg = (blockIdx.x & 7) * cpx + (blockIdx.x >> 3);
    const int m0 = (wg / nbx) * BM, n0 = (wg % nbx) * BN;
    const int wr = w >> 1, wc = w & 1;
    const int lr = l & 15, g = l >> 4;

    const ushort* W_ = (!GROUP || m0 < Msplit) ? Wt : Wt2;
    const float* b_ = (!GROUP || m0 < Msplit) ? bias : bias2;

    f32x4 acc[MI][NJ] = {};
    const int nt = K >> 5;

    #define STAGE(buf, kt)                                                        \
        do {                                                                      \
            const int k0s = (kt) << 5;                                            \
            for (int c = w; c < CA; c += 4)                                       \
                gload16(&A[(size_t)(m0 + c * 16 + lr) * K + k0s + 8 * g],         \
                        &Asm[buf][c * 512]);                                      \
            for (int c = w; c < CB; c += 4)                                       \
                gload16(&W_[(size_t)(n0 + c * 16 + lr) * K + k0s + 8 * g],        \
                        &Bsm[buf][c * 512]);                                      \
        } while (0)

    STAGE(0, 0);
    __syncthreads();
    int cur = 0;
    for (int t = 0; t < nt; ++t) {
        if (t + 1 < nt) STAGE(cur ^ 1, t + 1);
        FragU af[MI], bf4[NJ];
        #pragma unroll
        for (int mi = 0; mi < MI; ++mi)
            af[mi].u4 = *reinterpret_cast<const uint4*>(
                &Asm[cur][(wr * MI + mi) * 512 + l * 8]);
        #pragma unroll
        for (int nj = 0; nj < NJ; ++nj)
            bf4[nj].u4 = *reinterpret_cast<const uint4*>(
                &Bsm[cur][(wc * NJ + nj) * 512 + l * 8]);
        #pragma unroll
        for (int mi = 0; mi < MI; ++mi)
            #pragma unroll
            for (int nj = 0; nj < NJ; ++nj)
                acc[mi][nj] = __builtin_amdgcn_mfma_f32_16x16x32_bf16(
                    af[mi].v, bf4[nj].v, acc[mi][nj], 0, 0, 0);
        __syncthreads();
        cur ^= 1;
    }
    #undef STAGE

    float alpha = 0.f, beta = 0.f;
    if (FINAL) { alpha = alphap[0]; beta = betap[0]; }
    #pragma unroll
    for (int mi = 0; mi < MI; ++mi) {
        #pragma unroll
        for (int r = 0; r < 4; ++r) {
            const int m = m0 + wr * (MI * 16) + mi * 16 + g * 4 + r;
            float g0 = 0.f, g1 = 0.f, g2 = 0.f;
            if (OUT == 3) {
                const int bidx = m >> 10;
                g0 = alphap[3 * bidx];
                g1 = alphap[3 * bidx + 1];
                g2 = alphap[3 * bidx + 2];
            }
            #pragma unroll
            for (int nj = 0; nj < NJ; ++nj) {
                const int n = n0 + wc * (NJ * 16) + nj * 16 + lr;
                const size_t idx = (size_t)m * Nn + n;
                float v = acc[mi][nj][r] + b_[n];
                if (ACT == 1) v = gelu_f(v);
                if (FINAL)
                    v = bf2f(fusedb[idx]) + alpha * v + beta * bf2f(resb[idx]);
                if (OUT == 0) ((float*)Cv)[idx] = v;
                else if (OUT == 1) ((ushort*)Cv)[idx] = f2bf(v);
                else {  // OUT == 3: gate-fused epilogue
                    ((ushort*)Cv)[idx] = f2bf(
                        g0 * bf2f(fusedb[idx]) + g1 * bf2f(resb[idx]) + g2 * v);
                }
            }
        }
    }
}

// ---------------------------------------------------------------------------
// Merged prologue: blocks [0,3072) = weight convert+transpose (cvtw);
// blocks [3072,5120) = input convert (xh, xl, rb = 0.5*(h+l)).
// ---------------------------------------------------------------------------
__global__ __launch_bounds__(256) void prep0_k(
    const float* __restrict__ w0, const float* __restrict__ w1,
    const float* __restrict__ w2, const float* __restrict__ w3,
    const float* __restrict__ w4, const float* __restrict__ w5,
    const float* __restrict__ w6, const float* __restrict__ w7,
    ushort* __restrict__ dst,
    const float* __restrict__ h, const float* __restrict__ lf,
    ushort* __restrict__ xh, ushort* __restrict__ xl,
    ushort* __restrict__ rb)
{
    __shared__ ushort T[64][72];
    const int bid = blockIdx.x;
    if (bid >= 3072) {
        // ---- input convert part
        const size_t i = ((size_t)(bid - 3072) * 256 + threadIdx.x) * 8;
        const float4 h0 = *reinterpret_cast<const float4*>(h + i);
        const float4 h1 = *reinterpret_cast<const float4*>(h + i + 4);
        const float4 l0 = *reinterpret_cast<const float4*>(lf + i);
        const float4 l1 = *reinterpret_cast<const float4*>(lf + i + 4);
        FragU oh, ol, orr;
        oh.u[0] = pack2(h0.x, h0.y); oh.u[1] = pack2(h0.z, h0.w);
        oh.u[2] = pack2(h1.x, h1.y); oh.u[3] = pack2(h1.z, h1.w);
        ol.u[0] = pack2(l0.x, l0.y); ol.u[1] = pack2(l0.z, l0.w);
        ol.u[2] = pack2(l1.x, l1.y); ol.u[3] = pack2(l1.z, l1.w);
        orr.u[0] = pack2(0.5f * (h0.x + l0.x), 0.5f * (h0.y + l0.y));
        orr.u[1] = pack2(0.5f * (h0.z + l0.z), 0.5f * (h0.w + l0.w));
        orr.u[2] = pack2(0.5f * (h1.x + l1.x), 0.5f * (h1.y + l1.y));
        orr.u[3] = pack2(0.5f * (h1.z + l1.z), 0.5f * (h1.w + l1.w));
        *reinterpret_cast<uint4*>(xh + i) = oh.u4;
        *reinterpret_cast<uint4*>(xl + i) = ol.u4;
        *reinterpret_cast<uint4*>(rb + i) = orr.u4;
        return;
    }
    // ---- weight convert part (decoded from flat id: 24 x 16 x 8)
    const int id = bid / 384;            // weight index 0..7
    const int rem = bid % 384;
    const int by = rem / 24;             // k-tile
    const int bx = rem % 24;             // n-tile
    int K, Nn, off;
    const float* src;
    switch (id) {
        case 0: src = w0; K = 512;  Nn = 1536; off = WOFF_SQ;    break;
        case 1: src = w1; K = 512;  Nn = 1536; off = WOFF_PQ;    break;
        case 2: src = w2; K = 512;  Nn = 512;  off = WOFF_SPROJ; break;
        case 3: src = w3; K = 512;  Nn = 512;  off = WOFF_PPROJ; break;
        case 4: src = w4; K = 512;  Nn = 1024; off = WOFF_VF1;   break;
        case 5: src = w5; K = 1024; Nn = 512;  off = WOFF_VF2;   break;
        case 6: src = w6; K = 512;  Nn = 1024; off = WOFF_FR1;   break;
        default: src = w7; K = 1024; Nn = 512; off = WOFF_FR2;   break;
    }
    const int n0 = bx * 64, k0 = by * 64;
    if (n0 >= Nn || k0 >= K) return;
    const int t = threadIdx.x;
    const int q = t >> 6, e = t & 63;
    #pragma unroll 4
    for (int i = 0; i < 16; ++i) {
        const int kl = q * 16 + i;
        T[e][kl] = f2bf(src[(size_t)(k0 + kl) * Nn + n0 + e]);
    }
    __syncthreads();
    #pragma unroll 4
    for (int i = 0; i < 16; ++i) {
        const int nl = q * 16 + i;
        dst[(size_t)off + (size_t)(n0 + nl) * K + k0 + e] = T[nl][e];
    }
}

// ---------------------------------------------------------------------------
// Fused LN(1536) + head split + l2norm, bf16 in/out, both branches.
// VECTORIZED: lane l holds 8 contiguous elems per 512-chunk (q/k/v);
// per-head l2norm = 3-shuffle reduce over the aligned 8-lane group.
// ---------------------------------------------------------------------------
__global__ __launch_bounds__(256) void lnprep_k(ushort* __restrict__ x,
                                                const float* __restrict__ lng0,
                                                const float* __restrict__ lnb0,
                                                const float* __restrict__ lng1,
                                                const float* __restrict__ lnb1,
                                                const float* __restrict__ temp,
                                                ushort* __restrict__ Kb,
                                                ushort* __restrict__ Vt)
{
    __shared__ ushort Vs[8 * 512];
    const int w = threadIdx.x >> 6, l = threadIdx.x & 63;
    const int n0 = blockIdx.x * 8;
    const float L2E = 1.4426950408889634f;
    const float* lng = (n0 < 8192) ? lng0 : lng1;
    const float* lnb = (n0 < 8192) ? lnb0 : lnb1;
    const int hd8 = l >> 3;          // head for q/k chunks
    const int d8  = (l & 7) * 8;     // dim base within head
    const float tL = temp[hd8] * L2E;

    float gq[8], bq[8], gk[8], bk[8], gv[8], bv[8];
    #pragma unroll
    for (int e = 0; e < 8; ++e) {
        gq[e] = lng[8 * l + e];          bq[e] = lnb[8 * l + e];
        gk[e] = lng[512 + 8 * l + e];    bk[e] = lnb[512 + 8 * l + e];
        gv[e] = lng[1024 + 8 * l + e];   bv[e] = lnb[1024 + 8 * l + e];
    }

    #pragma unroll
    for (int rr = 0; rr < 2; ++rr) {
        const int row = n0 + w * 2 + rr;
        const int bb = row >> 10;        // 0..15
        const int n = row & 1023;
        ushort* xr = x + (size_t)row * D3_;
        FragU cq, ck, cv;
        cq.u4 = *reinterpret_cast<const uint4*>(xr + 8 * l);
        ck.u4 = *reinterpret_cast<const uint4*>(xr + 512 + 8 * l);
        cv.u4 = *reinterpret_cast<const uint4*>(xr + 1024 + 8 * l);
        float q[8], k[8], v[8];
        float s = 0.f, ss = 0.f;
        #pragma unroll
        for (int e = 0; e < 8; ++e) {
            q[e] = bf2f(cq.s[e]); k[e] = bf2f(ck.s[e]); v[e] = bf2f(cv.s[e]);
            s += q[e] + k[e] + v[e];
            ss += q[e] * q[e] + k[e] * k[e] + v[e] * v[e];
        }
        #pragma unroll
        for (int off = 32; off; off >>= 1) {
            s += __shfl_xor(s, off);
            ss += __shfl_xor(ss, off);
        }
        const float mu = s * (1.0f / D3_);
        const float var = ss * (1.0f / D3_) - mu * mu;
        const float rs = rsqrtf(var + 1e-5f);
        float sq = 0.f, sk = 0.f;
        #pragma unroll
        for (int e = 0; e < 8; ++e) {
            q[e] = (q[e] - mu) * rs * gq[e] + bq[e];
            k[e] = (k[e] - mu) * rs * gk[e] + bk[e];
            v[e] = (v[e] - mu) * rs * gv[e] + bv[e];
            sq += q[e] * q[e];
            sk += k[e] * k[e];
        }
        #pragma unroll
        for (int off = 4; off; off >>= 1) {
            sq += __shfl_xor(sq, off);
            sk += __shfl_xor(sk, off);
        }
        const float qs = tL / fmaxf(sqrtf(sq), 1e-12f);
        const float ks = 1.0f / fmaxf(sqrtf(sk), 1e-12f);
        FragU oq, ok, ov;
        #pragma unroll
        for (int e = 0; e < 8; ++e) {
            oq.s[e] = f2bf(q[e] * qs);
            ok.s[e] = f2bf(k[e] * ks);
            ov.s[e] = f2bf(v[e]);
        }
        *reinterpret_cast<uint4*>(xr + 8 * l) = oq.u4;   // Q in place
        *reinterpret_cast<uint4*>(
            &Kb[((size_t)(bb * 8 + hd8) * N_ + n) * HD_ + d8]) = ok.u4;
        *reinterpret_cast<uint4*>(&Vs[(w * 2 + rr) * 512 + 8 * l]) = ov.u4;
    }
    __syncthreads();
    const int bb = n0 >> 10;
    #pragma unroll
    for (int it = 0; it < 2; ++it) {
        const int combo = threadIdx.x + it * 256;   // h*64 + d
        FragU f;
        #pragma unroll
        for (int tok = 0; tok < 8; ++tok) f.s[tok] = Vs[tok * 512 + combo];
        *reinterpret_cast<uint4*>(
            &Vt[((size_t)(bb * 8 + (combo >> 6)) * HD_ + (combo & 63)) * N_ + (n0 & 1023)]) = f.u4;
    }
}

// ---------------------------------------------------------------------------
// Flash-style cosine attention, both branches. grid 1024, XCD-swizzled.
// Round-11 structure (best measured): double-buffered Ks/Vs LDS (one barrier
// per KV tile), setprio around MFMA cluster, softmax shift folded into MFMA
// C-init, lsum via ones-MFMA.
// ---------------------------------------------------------------------------
__global__ __launch_bounds__(256) void fattn_k(const ushort* __restrict__ Qu,
                                               const ushort* __restrict__ Kb,
                                               const ushort* __restrict__ Vt,
                                               const float* __restrict__ temp,
                                               ushort* __restrict__ out)
{
    __shared__ ushort Ks[2][64 * 72];
    __shared__ ushort Vs[2][64 * 72];
    const int tid = threadIdx.x;
    const int cpx = gridDim.x >> 3;
    const int wg = (blockIdx.x & 7) * cpx + (blockIdx.x >> 3);
    const int nb = wg & 7;
    const int h  = (wg >> 3) & 7;
    const int bb = wg >> 6;          // 0..15
    const int bh = bb * 8 + h;       // 0..127
    const int n0 = nb * 128;
    const int w  = tid >> 6;
    const int l  = tid & 63;
    const int lr = l & 15;
    const int g  = l >> 4;
    const float m2 = fabsf(temp[h]) * 1.4426950408889634f;
    const f32x4 mInit = {-m2, -m2, -m2, -m2};

    FragU ones;
    ones.u[0] = ones.u[1] = ones.u[2] = ones.u[3] = 0x3F803F80u;

    const int qb = n0 + w * 32;
    FragU qa0, qa1, qb0, qb1;
    {
        const size_t rb0 = (size_t)(bb * N_ + qb + lr) * D3_ + h * 64 + 8 * g;
        const size_t rb1 = (size_t)(bb * N_ + qb + 16 + lr) * D3_ + h * 64 + 8 * g;
        qa0.u4 = *reinterpret_cast<const uint4*>(&Qu[rb0]);
        qa1.u4 = *reinterpret_cast<const uint4*>(&Qu[rb0 + 32]);
        qb0.u4 = *reinterpret_cast<const uint4*>(&Qu[rb1]);
        qb1.u4 = *reinterpret_cast<const uint4*>(&Qu[rb1 + 32]);
    }

    f32x4 OA[4] = {};
    f32x4 OB[4] = {};
    f32x4 LSA = {0.f, 0.f, 0.f, 0.f};
    f32x4 LSB = {0.f, 0.f, 0.f, 0.f};

    const ushort* kbase = Kb + (size_t)bh * N_ * HD_;
    const ushort* vbase = Vt + (size_t)bh * HD_ * N_;
    const int sr = tid >> 3;
    const int sc = (tid & 7) * 8;
    uint4 k0r, k1r, v0r, v1r;

    #define LOADT(kt)                                                           \
        do {                                                                    \
            const ushort* ks_ = kbase + (size_t)((kt) * 64) * HD_;              \
            const ushort* vs_ = vbase + (kt) * 64;                              \
            k0r = *reinterpret_cast<const uint4*>(ks_ + sr * HD_ + sc);         \
            k1r = *reinterpret_cast<const uint4*>(ks_ + (sr + 32) * HD_ + sc);  \
            v0r = *reinterpret_cast<const uint4*>(vs_ + (size_t)sr * N_ + sc);  \
            v1r = *reinterpret_cast<const uint4*>(vs_ + (size_t)(sr + 32) * N_ + sc); \
        } while (0)
    #define WRITET(p)                                                           \
        do {                                                                    \
            *reinterpret_cast<uint4*>(&Ks[p][sr * 72 + sc]) = k0r;              \
            *reinterpret_cast<uint4*>(&Ks[p][(sr + 32) * 72 + sc]) = k1r;       \
            *reinterpret_cast<uint4*>(&Vs[p][sr * 72 + sc]) = v0r;              \
            *reinterpret_cast<uint4*>(&Vs[p][(sr + 32) * 72 + sc]) = v1r;       \
        } while (0)

    LOADT(0);
    WRITET(0);

    #pragma unroll 1
    for (int kt = 0; kt < 16; ++kt) {
        const int p = kt & 1;
        __syncthreads();               // buf p fully written; buf p^1 free
        if (kt < 15) LOADT(kt + 1);    // global->reg, overlaps compute

        unsigned paA[2][4], paB[2][4];
        #pragma unroll
        for (int j = 0; j < 4; ++j) {
            FragU ka, kc;
            ka.u4 = *reinterpret_cast<const uint4*>(&Ks[p][(j * 16 + lr) * 72 + 8 * g]);
            kc.u4 = *reinterpret_cast<const uint4*>(&Ks[p][(j * 16 + lr) * 72 + 32 + 8 * g]);
            f32x4 sA = mInit, sB = mInit;
            sA = __builtin_amdgcn_mfma_f32_16x16x32_bf16(ka.v, qa0.v, sA, 0, 0, 0);
            sA = __builtin_amdgcn_mfma_f32_16x16x32_bf16(kc.v, qa1.v, sA, 0, 0, 0);
            sB = __builtin_amdgcn_mfma_f32_16x16x32_bf16(ka.v, qb0.v, sB, 0, 0, 0);
            sB = __builtin_amdgcn_mfma_f32_16x16x32_bf16(kc.v, qb1.v, sB, 0, 0, 0);
            float pA[4], pB[4];
            #pragma unroll
            for (int r = 0; r < 4; ++r) {
                pA[r] = exp2_fast(sA[r]);
                pB[r] = exp2_fast(sB[r]);
            }
            paA[j >> 1][2 * (j & 1) + 0] = pack2(pA[0], pA[1]);
            paA[j >> 1][2 * (j & 1) + 1] = pack2(pA[2], pA[3]);
            paB[j >> 1][2 * (j & 1) + 0] = pack2(pB[0], pB[1]);
            paB[j >> 1][2 * (j & 1) + 1] = pack2(pB[2], pB[3]);
        }

        __builtin_amdgcn_s_setprio(1);
        #pragma unroll
        for (int ks = 0; ks < 2; ++ks) {
            FragU fa, fb2;
            fa.u[0] = paA[ks][0]; fa.u[1] = paA[ks][1];
            fa.u[2] = paA[ks][2]; fa.u[3] = paA[ks][3];
            fb2.u[0] = paB[ks][0]; fb2.u[1] = paB[ks][1];
            fb2.u[2] = paB[ks][2]; fb2.u[3] = paB[ks][3];
            LSA = __builtin_amdgcn_mfma_f32_16x16x32_bf16(fa.v, ones.v, LSA, 0, 0, 0);
            LSB = __builtin_amdgcn_mfma_f32_16x16x32_bf16(fb2.v, ones.v, LSB, 0, 0, 0);
            #pragma unroll
            for (int s4 = 0; s4 < 4; ++s4) {
                FragU vb;
                const int vi = (lr + 16 * s4) * 72 + ks * 32 + 4 * g;
                *reinterpret_cast<uint2*>(&vb.u[0]) =
                    *reinterpret_cast<const uint2*>(&Vs[p][vi]);
                *reinterpret_cast<uint2*>(&vb.u[2]) =
                    *reinterpret_cast<const uint2*>(&Vs[p][vi + 16]);
                OA[s4] = __builtin_amdgcn_mfma_f32_16x16x32_bf16(fa.v, vb.v, OA[s4], 0, 0, 0);
                OB[s4] = __builtin_amdgcn_mfma_f32_16x16x32_bf16(fb2.v, vb.v, OB[s4], 0, 0, 0);
            }
        }
        __builtin_amdgcn_s_setprio(0);

        if (kt < 15) WRITET(p ^ 1);    // other buffer: no wave reads it now
    }
    #undef LOADT
    #undef WRITET

    // LS D-layout: row (= q) is (lane>>4)*4 + r — exactly the rows this lane
    // stores below, so no cross-lane reduction is needed.
    ushort* outp = out + ((size_t)(bb * N_) + qb) * D_ + h * HD_;
    #pragma unroll
    for (int r = 0; r < 4; ++r) {
        const float iA = 1.0f / LSA[r];
        const float iB = 1.0f / LSB[r];
        ushort* rowA = outp + (size_t)(4 * g + r) * D_;
        ushort* rowB = outp + (size_t)(16 + 4 * g + r) * D_;
        #pragma unroll
        for (int s4 = 0; s4 < 4; ++s4) {
            rowA[s4 * 16 + lr] = f2bf(OA[s4][r] * iA);
            rowB[s4 * 16 + lr] = f2bf(OB[s4][r] * iB);
        }
    }
}

// ---------------------------------------------------------------------------
// Merged cvtadd + means: one pass over spec/spat computes
//   Sb = bf16(spec + spat)   AND   Gp column partial sums (32-row chunks).
// grid = B*32 = 256 blocks, 256 thr (2 cols each).
// ---------------------------------------------------------------------------
__global__ __launch_bounds__(256) void sums_k(const ushort* __restrict__ spec,
                                              const ushort* __restrict__ spat,
                                              ushort* __restrict__ Sb,
                                              float* __restrict__ Gp)
{
    const int b = blockIdx.x >> 5;
    const int ch = blockIdx.x & 31;
    const int n0 = ch * 32;
    const int d0 = threadIdx.x * 2;
    float s1a = 0.f, s1b = 0.f, s2a = 0.f, s2b = 0.f;
    #pragma unroll 4
    for (int n = 0; n < 32; ++n) {
        const size_t idx = ((size_t)(b * N_) + n0 + n) * D_ + d0;
        ushort u1[2], u2[2];
        *reinterpret_cast<unsigned*>(u1) = *reinterpret_cast<const unsigned*>(spec + idx);
        *reinterpret_cast<unsigned*>(u2) = *reinterpret_cast<const unsigned*>(spat + idx);
        const float a0 = bf2f(u1[0]), a1 = bf2f(u1[1]);
        const float c0 = bf2f(u2[0]), c1 = bf2f(u2[1]);
        s1a += a0; s1b += a1;
        s2a += c0; s2b += c1;
        ushort o[2];
        o[0] = f2bf(a0 + c0);
        o[1] = f2bf(a1 + c1);
        *reinterpret_cast<unsigned*>(Sb + idx) = *reinterpret_cast<unsigned*>(o);
    }
    float* gp = Gp + (size_t)blockIdx.x * 1024;
    gp[d0] = s1a; gp[d0 + 1] = s1b;
    gp[512 + d0] = s2a; gp[512 + d0 + 1] = s2b;
}

// ---------------------------------------------------------------------------
// gate GEMV: y[b][512] = mean-vec(xs) @ ag_w1 + b1. grid (8 jc, 8 b).
// ---------------------------------------------------------------------------
__global__ __launch_bounds__(256) void gate1_k(const float* __restrict__ Gp,
                                               const float* __restrict__ w1,
                                               const float* __restrict__ b1,
                                               float* __restrict__ y)
{
    __shared__ float xs[1024];
    __shared__ float red[4][64];
    const int jc = blockIdx.x, b = blockIdx.y, tid = threadIdx.x;
    for (int k = tid; k < 1024; k += 256) {
        float s = 0.f;
        #pragma unroll 8
        for (int c = 0; c < 32; ++c) s += Gp[(size_t)(b * 32 + c) * 1024 + k];
        xs[k] = s * (1.0f / N_);
    }
    __syncthreads();
    const int jl = tid & 63;
    const int jj = jc * 64 + jl;
    const int seg = tid >> 6;
    float acc = 0.f;
    const float* wp = w1 + (size_t)(seg * 256) * 512 + jj;
    const float* xp = xs + seg * 256;
    #pragma unroll 8
    for (int k = 0; k < 256; ++k) acc += xp[k] * wp[(size_t)k * 512];
    red[seg][jl] = acc;
    __syncthreads();
    if (tid < 64)
        y[b * 512 + jc * 64 + tid] =
            red[0][tid] + red[1][tid] + red[2][tid] + red[3][tid] + b1[jc * 64 + tid];
}

// ---------------------------------------------------------------------------
// gate tail: LN(512) -> GELU -> @ag_w2[512,3]+b2 -> softmax. grid = 8 blocks.
// ---------------------------------------------------------------------------
__global__ __launch_bounds__(256) void gate2_k(const float* __restrict__ y,
                                               const float* __restrict__ lng,
                                               const float* __restrict__ lnb,
                                               const float* __restrict__ w2,
                                               const float* __restrict__ b2,
                                               float* __restrict__ gate)
{
    __shared__ float red[4];
    const int b = blockIdx.x, tid = threadIdx.x;
    const float v0 = y[b * 512 + tid];
    const float v1 = y[b * 512 + 256 + tid];
    const float s = blk_sum(v0 + v1, red);
    const float ss = blk_sum(v0 * v0 + v1 * v1, red);
    const float mu = s * (1.0f / 512.0f);
    const float var = ss * (1.0f / 512.0f) - mu * mu;
    const float rs = rsqrtf(var + 1e-5f);
    const float z0 = gelu_f((v0 - mu) * rs * lng[tid] + lnb[tid]);
    const float z1 = gelu_f((v1 - mu) * rs * lng[tid + 256] + lnb[tid + 256]);
    float p0 = z0 * w2[tid * 3 + 0] + z1 * w2[(tid + 256) * 3 + 0];
    float p1 = z0 * w2[tid * 3 + 1] + z1 * w2[(tid + 256) * 3 + 1];
    float p2 = z0 * w2[tid * 3 + 2] + z1 * w2[(tid + 256) * 3 + 2];
    p0 = blk_sum(p0, red);
    p1 = blk_sum(p1, red);
    p2 = blk_sum(p2, red);
    if (tid == 0) {
        p0 += b2[0]; p1 += b2[1]; p2 += b2[2];
        const float m = fmaxf(p0, fmaxf(p1, p2));
        const float e0 = expf(p0 - m), e1 = expf(p1 - m), e2 = expf(p2 - m);
        const float inv = 1.0f / (e0 + e1 + e2);
        gate[b * 3 + 0] = e0 * inv;
        gate[b * 3 + 1] = e1 * inv;
        gate[b * 3 + 2] = e2 * inv;
    }
}

// ---------------------------------------------------------------------------
extern "C" void kernel_launch(void* const* d_in, const int* in_sizes, int n_in,
                              void* d_out, int out_size, void* d_ws, size_t ws_size,
                              hipStream_t stream)
{
    const float* hsi    = (const float*)d_in[0];
    const float* lidar  = (const float*)d_in[1];
    const float* temp   = (const float*)d_in[2];
    const float* sq_w   = (const float*)d_in[3];
    const float* sq_b   = (const float*)d_in[4];
    const float* sq_lng = (const float*)d_in[5];
    const float* sq_lnb = (const float*)d_in[6];
    const float* sproj_w = (const float*)d_in[7];
    const float* sproj_b = (const float*)d_in[8];
    const float* pq_w   = (const float*)d_in[9];
    const float* pq_b   = (const float*)d_in[10];
    const float* pq_lng = (const float*)d_in[11];
    const float* pq_lnb = (const float*)d_in[12];
    const float* pproj_w = (const float*)d_in[13];
    const float* pproj_b = (const float*)d_in[14];
    const float* vf_w1  = (const float*)d_in[15];
    const float* vf_b1  = (const float*)d_in[16];
    const float* vf_w2  = (const float*)d_in[17];
    const float* vf_b2  = (const float*)d_in[18];
    const float* ag_w1  = (const float*)d_in[19];
    const float* ag_b1  = (const float*)d_in[20];
    const float* ag_lng = (const float*)d_in[21];
    const float* ag_lnb = (const float*)d_in[22];
    const float* ag_w2  = (const float*)d_in[23];
    const float* ag_b2  = (const float*)d_in[24];
    const float* fr_w1  = (const float*)d_in[25];
    const float* fr_b1  = (const float*)d_in[26];
    const float* fr_w2  = (const float*)d_in[27];
    const float* fr_b2  = (const float*)d_in[28];
    const float* alpha  = (const float*)d_in[29];
    const float* beta   = (const float*)d_in[30];
    float* out = (float*)d_out;

    // ---- workspace layout (ushort units; peak ~117.4 MB) ----
    ushort* base = (ushort*)d_ws;
    ushort* Qkv  = base;                 // [16384][1536] bf16 (50.3 MB), qkv+Q
    ushort* Ob   = base;                 //   after attn: [16384][512] proj out
    ushort* Sb   = base + 8388608;       //   [8192][512] spec+spat bf16
    ushort* fb   = base + 16777216;      //   [8192][512] fused bf16
    float*  Gp   = (float*)(base + 20971520);  // [256][1024] f32 partials
    float*  gate = Gp + 262144;
    float*  ybuf = gate + 64;            //   [8][512]
    ushort* Kb   = base + 25165824;      // [128][1024][64] bf16 (16.8 MB)
    ushort* Vt   = base + 33554432;      // [128][64][1024] bf16 (16.8 MB)
    ushort* Hb   = base + 25165824;      //   after attn: [8192][1024] MLP hidden
    ushort* Ab   = base + 41943040;      // [16384][512] attn out bf16 (16.8 MB)
    ushort* Xb   = base + 41943040;      //   (pre-attn) [16384][512] bf16 inputs
    ushort* Wb   = base + 50331648;      // bf16 weights pool (8.4 MB)
    ushort* Rb   = base + 54525952;      // [8192][512] bf16 0.5*(hsi+lidar)

    const dim3 blk(256);

    // ---- merged prologue: weight transpose + input convert (one dispatch)
    prep0_k<<<5120, blk, 0, stream>>>(sq_w, pq_w, sproj_w, pproj_w,
                                      vf_w1, vf_w2, fr_w1, fr_w2, Wb,
                                      hsi, lidar, Xb, Xb + (size_t)M_ * D_, Rb);

    // ---- qkv for BOTH branches (grouped, 128x128 tile — proven best)
    pgemm_k<128,128,0,1,false,true><<<1536, blk, 0, stream>>>(
        Xb, Wb + WOFF_SQ, Wb + WOFF_PQ, sq_b, pq_b, M_,
        Qkv, 12, D3_, D_, nullptr, nullptr, nullptr, nullptr);

    // ---- LN + l2norm + K/V prep, both branches (vectorized)
    lnprep_k<<<2048, blk, 0, stream>>>(Qkv, sq_lng, sq_lnb, pq_lng, pq_lnb,
                                       temp, Kb, Vt);

    // ---- attention, both branches
    fattn_k<<<1024, blk, 0, stream>>>(Qkv, Kb, Vt, temp, Ab);

    // ---- projection for BOTH branches (grouped) -> Ob bf16
    pgemm_k<128,64,0,1,false,true><<<1024, blk, 0, stream>>>(
        Ab, Wb + WOFF_SPROJ, Wb + WOFF_PPROJ, sproj_b, pproj_b, M_,
        Ob, 8, D_, D_, nullptr, nullptr, nullptr, nullptr);

    const ushort* spec_b = Ob;
    const ushort* spat_b = Ob + (size_t)M_ * D_;

    // ---- one pass: Sb = spec+spat AND gate column partials; gate MLP (2-stage)
    sums_k<<<256, blk, 0, stream>>>(spec_b, spat_b, Sb, Gp);
    gate1_k<<<dim3(8, 8), blk, 0, stream>>>(Gp, ag_w1, ag_b1, ybuf);
    gate2_k<<<B_, blk, 0, stream>>>(ybuf, ag_lng, ag_lnb, ag_w2, ag_b2, gate);

    // ---- volumetric MLP: Hb = gelu(Sb@vf_w1); vf2 fuses the gate combine:
    //      fb = bf16(g0*spec + g1*spat + g2*(Hb@vf_w2 + b2))
    pgemm_k<128,64,1,1,false,false><<<1024, blk, 0, stream>>>(
        Sb, Wb + WOFF_VF1, nullptr, vf_b1, nullptr, 0,
        Hb, 16, 1024, D_, nullptr, nullptr, nullptr, nullptr);
    pgemm_k<128,64,0,3,false,false><<<512, blk, 0, stream>>>(
        Hb, Wb + WOFF_VF2, nullptr, vf_b2, nullptr, 0,
        fb, 8, D_, 1024, spec_b, spat_b, gate, nullptr);

    // ---- recal MLP + final combine
    pgemm_k<128,64,1,1,false,false><<<1024, blk, 0, stream>>>(
        fb, Wb + WOFF_FR1, nullptr, fr_b1, nullptr, 0,
        Hb, 16, 1024, D_, nullptr, nullptr, nullptr, nullptr);
    pgemm_k<128,64,0,0,true,false><<<512, blk, 0, stream>>>(
        Hb, Wb + WOFF_FR2, nullptr, fr_b2, nullptr, 0,
        out, 8, D_, 1024, fb, Rb, alpha, beta);
}